// Round 7
// baseline (175.831 us; speedup 1.0000x reference)
//
#include <hip/hip_runtime.h>
#include <math.h>

// Problem: B=4, L=1024, C1=1024, C2=1024, K=32, K_IN=32, g=256.
// N = B*L = 4096 rows. All f32.
//
// ws layout (floats):
//   wT      [1024*1024]            off 0
//   linT    [2][256*1024]          off 1048576
//   xc      [2][4096*256]          off 1572864
//   partials[256][4][256]          off 3670016
//   sc      [2][2][256]            off 3932160
//   p0      [8192][1024]           off 3933184   (k-half 0 partial logits)
//   tidx    [8192][32] (u32)       off 12321792
//   tval    [8192][32]             off 12583936
//   p1      [8192][1024]           off 12846080  (k-half 1 partial logits)
// total ~21.2M floats = 84.9 MB (falls back to full-K logits if ws smaller)

__device__ __forceinline__ unsigned int ford(float f) {
    unsigned int b = __float_as_uint(f);
    return (b & 0x80000000u) ? ~b : (b | 0x80000000u);
}

// ---------------- generic 32x32 tiled transpose: in (R,C) -> out (C,R) -------
__global__ __launch_bounds__(256) void transpose_k(const float* __restrict__ in,
                                                   float* __restrict__ out,
                                                   int R, int C) {
    __shared__ float tile[32][33];
    int c0 = blockIdx.x * 32, r0 = blockIdx.y * 32;
    int tx = threadIdx.x, ty = threadIdx.y;  // block (32,8)
#pragma unroll
    for (int i = 0; i < 32; i += 8)
        tile[ty + i][tx] = in[(size_t)(r0 + ty + i) * C + c0 + tx];
    __syncthreads();
#pragma unroll
    for (int i = 0; i < 32; i += 8)
        out[(size_t)(c0 + ty + i) * R + r0 + tx] = tile[tx][ty + i];
}

// ---------------- grouped 1x1 conv (4->1) for both branches + partial stats --
__global__ __launch_bounds__(256) void conv_stats_k(
    const float* __restrict__ x,
    const float* __restrict__ so_w, const float* __restrict__ so_b,
    const float* __restrict__ si_w, const float* __restrict__ si_b,
    float* __restrict__ xc, float* __restrict__ partials) {
    int g = threadIdx.x;          // channel 0..255
    int n0 = blockIdx.x * 16;     // 256 blocks x 16 rows
    float4 wo = ((const float4*)so_w)[g]; float bo = so_b[g];
    float4 wi = ((const float4*)si_w)[g]; float bi = si_b[g];
    float so_s = 0.f, so_q = 0.f, si_s = 0.f, si_q = 0.f;
#pragma unroll
    for (int r = 0; r < 16; ++r) {
        int n = n0 + r;
        float4 xv = ((const float4*)x)[n * 256 + g];
        float co = fmaf(xv.x, wo.x, fmaf(xv.y, wo.y, fmaf(xv.z, wo.z, fmaf(xv.w, wo.w, bo))));
        float ci = fmaf(xv.x, wi.x, fmaf(xv.y, wi.y, fmaf(xv.z, wi.z, fmaf(xv.w, wi.w, bi))));
        xc[n * 256 + g] = co;
        xc[1048576 + n * 256 + g] = ci;
        so_s += co; so_q += co * co;
        si_s += ci; si_q += ci * ci;
    }
    int b = blockIdx.x;
    partials[(b * 4 + 0) * 256 + g] = so_s;
    partials[(b * 4 + 1) * 256 + g] = so_q;
    partials[(b * 4 + 2) * 256 + g] = si_s;
    partials[(b * 4 + 3) * 256 + g] = si_q;
}

// ---------------- finalize BN stats -> per-channel scale/shift ---------------
__global__ __launch_bounds__(256) void stats_k(
    const float* __restrict__ partials,
    const float* __restrict__ g_so, const float* __restrict__ b_so,
    const float* __restrict__ g_si, const float* __restrict__ b_si,
    float* __restrict__ sc) {
    int g = threadIdx.x;
    int br = blockIdx.x;  // 0 = so, 1 = si
    float s = 0.f, q = 0.f;
    for (int b = 0; b < 256; ++b) {
        s += partials[(b * 4 + br * 2 + 0) * 256 + g];
        q += partials[(b * 4 + br * 2 + 1) * 256 + g];
    }
    float mean = s * (1.f / 4096.f);
    float var  = q * (1.f / 4096.f) - mean * mean;  // biased, matches ref
    float rstd = rsqrtf(var + 1e-5f);
    float gm = br ? g_si[g] : g_so[g];
    float bt = br ? b_si[g] : b_so[g];
    float scale = gm * rstd;
    sc[br * 512 + g]       = scale;
    sc[br * 512 + 256 + g] = fmaf(-mean, scale, bt);
}

#define FMA_BLOCK(A0, A1, WA, WB)                                   \
    {                                                               \
        _Pragma("unroll")                                           \
        for (int i = 0; i < 4; ++i) {                               \
            float wa = (&WA.x)[i], wb = (&WB.x)[i];                 \
            accA[0][i].x = fmaf(A0.x, wa, accA[0][i].x);            \
            accA[0][i].y = fmaf(A0.y, wa, accA[0][i].y);            \
            accA[0][i].z = fmaf(A0.z, wa, accA[0][i].z);            \
            accA[0][i].w = fmaf(A0.w, wa, accA[0][i].w);            \
            accA[1][i].x = fmaf(A1.x, wa, accA[1][i].x);            \
            accA[1][i].y = fmaf(A1.y, wa, accA[1][i].y);            \
            accA[1][i].z = fmaf(A1.z, wa, accA[1][i].z);            \
            accA[1][i].w = fmaf(A1.w, wa, accA[1][i].w);            \
            accB[0][i].x = fmaf(A0.x, wb, accB[0][i].x);            \
            accB[0][i].y = fmaf(A0.y, wb, accB[0][i].y);            \
            accB[0][i].z = fmaf(A0.z, wb, accB[0][i].z);            \
            accB[0][i].w = fmaf(A0.w, wb, accB[0][i].w);            \
            accB[1][i].x = fmaf(A1.x, wb, accB[1][i].x);            \
            accB[1][i].y = fmaf(A1.y, wb, accB[1][i].y);            \
            accB[1][i].z = fmaf(A1.z, wb, accB[1][i].z);            \
            accB[1][i].w = fmaf(A1.w, wb, accB[1][i].w);            \
        }                                                           \
    }

// ---------------- BN+GELU fused + split-K (4096x256)@(256x1024) f32 GEMM -----
// Block = 32 rows x 512 cols x 128 k; 4 symmetric waves (one per 8-row group);
// per-thread 8x8 tile; weight addressing = one pointer bump + imm offsets per
// k (addr VALU ~6% of FMA). 1024 blocks = 4/CU = 4 waves/SIMD. Each block
// writes a k-half partial; reduction + bias fused into topk_k.
__global__ __launch_bounds__(256, 4) void logits_split_k(
    const float* __restrict__ xc, const float* __restrict__ sc,
    const float* __restrict__ linT,
    float* __restrict__ p0, float* __restrict__ p1) {
    int t = threadIdx.x;
    int bx = blockIdx.x;            // 256: n-block (bx>>1), k-half (bx&1)
    int n0 = (bx >> 1) * 32;
    int kh = bx & 1, koff = kh * 128;
    int cb = blockIdx.y;            // col half (512 cols)
    int br = blockIdx.z;
    int wave = t >> 6, lane = t & 63;
    int rh = wave;                  // rows 8*rh .. 8*rh+7
    int col0 = cb * 512 + lane * 4; // cols col0..+3 and col0+256..+259

    __shared__ float xaT[130][32];  // [k][row], 2 pad rows for dangling prefetch

    const float* xcb = xc + (size_t)br * 1048576;
    const float* lt  = linT + (size_t)br * 262144;

    // ---- stage xa^T for this k-half (BN + exact GELU): 2 rows x 8 k / thread
    {
        int kb8 = (t >> 4) * 8;     // 0..120
        int r2  = (t & 15) * 2;     // 0..30
        const float* scp = sc + br * 512 + koff + kb8;
        float4 sc0 = *(const float4*)scp;
        float4 sc1 = *(const float4*)(scp + 4);
        float4 sh0 = *(const float4*)(scp + 256);
        float4 sh1 = *(const float4*)(scp + 260);
        const float* x0 = xcb + (size_t)(n0 + r2) * 256 + koff + kb8;
        float4 ca0 = *(const float4*)x0;
        float4 ca1 = *(const float4*)(x0 + 4);
        float4 cb0 = *(const float4*)(x0 + 256);
        float4 cb1 = *(const float4*)(x0 + 260);
#pragma unroll
        for (int j = 0; j < 8; ++j) {
            float scl = j < 4 ? (&sc0.x)[j] : (&sc1.x)[j - 4];
            float shf = j < 4 ? (&sh0.x)[j] : (&sh1.x)[j - 4];
            float c0  = j < 4 ? (&ca0.x)[j] : (&ca1.x)[j - 4];
            float c1  = j < 4 ? (&cb0.x)[j] : (&cb1.x)[j - 4];
            float z0 = fmaf(c0, scl, shf);
            float z1 = fmaf(c1, scl, shf);
            float2 gw;
            gw.x = 0.5f * z0 * (1.f + erff(z0 * 0.70710678f));
            gw.y = 0.5f * z1 * (1.f + erff(z1 * 0.70710678f));
            *(float2*)&xaT[kb8 + j][r2] = gw;
        }
    }
    __syncthreads();  // the only barrier

    float4 accA[2][4];              // [row-quad][col i], components = rows
    float4 accB[2][4];
#pragma unroll
    for (int a = 0; a < 2; ++a)
#pragma unroll
        for (int i = 0; i < 4; ++i) {
            accA[a][i] = make_float4(0.f, 0.f, 0.f, 0.f);
            accB[a][i] = make_float4(0.f, 0.f, 0.f, 0.f);
        }

    // ---- 128-k loop, 1-deep prefetch, pointer-bump addressing ----
    // Dangling prefetch on the last iteration reads 1 row past the k-half:
    // global stays inside ws (linT's other half / xc region), LDS hits pad.
    const float* wp = lt + (size_t)koff * 1024 + col0;
    const float* xab = &xaT[0][8 * rh];
    float4 wA0 = *(const float4*)wp;
    float4 wB0 = *(const float4*)(wp + 256);
    float4 a00 = *(const float4*)xab;
    float4 a10 = *(const float4*)(xab + 4);
    for (int k = 0; k < 128; k += 2) {
        float4 wA1 = *(const float4*)(wp + 1024);
        float4 wB1 = *(const float4*)(wp + 1280);
        float4 a01 = *(const float4*)(xab + 32);
        float4 a11 = *(const float4*)(xab + 36);
        FMA_BLOCK(a00, a10, wA0, wB0);
        wA0 = *(const float4*)(wp + 2048);
        wB0 = *(const float4*)(wp + 2304);
        a00 = *(const float4*)(xab + 64);
        a10 = *(const float4*)(xab + 68);
        FMA_BLOCK(a01, a11, wA1, wB1);
        wp += 2048;
        xab += 64;
    }

    // ---- write k-half partial (no bias; fused into topk) ----
    float* pp = (kh ? p1 : p0) +
                ((size_t)br * 4096 + n0 + 8 * rh) * 1024 + col0;
#pragma unroll
    for (int a = 0; a < 2; ++a)
#pragma unroll
        for (int ri = 0; ri < 4; ++ri) {
            float4 vA, vB;
            vA.x = (&accA[a][0].x)[ri];
            vA.y = (&accA[a][1].x)[ri];
            vA.z = (&accA[a][2].x)[ri];
            vA.w = (&accA[a][3].x)[ri];
            vB.x = (&accB[a][0].x)[ri];
            vB.y = (&accB[a][1].x)[ri];
            vB.z = (&accB[a][2].x)[ri];
            vB.w = (&accB[a][3].x)[ri];
            *(float4*)&pp[(size_t)(a * 4 + ri) * 1024]       = vA;
            *(float4*)&pp[(size_t)(a * 4 + ri) * 1024 + 256] = vB;
        }
}

// ---------------- fallback full-K logits (round-6 structure) -----------------
__global__ __launch_bounds__(256, 4) void logits_full_k(
    const float* __restrict__ xc, const float* __restrict__ sc,
    const float* __restrict__ linT,
    const float* __restrict__ so_lb, const float* __restrict__ si_lb,
    float* __restrict__ logits) {
    int t = threadIdx.x;
    int n0 = blockIdx.x * 16;
    int cb = blockIdx.y;
    int br = blockIdx.z;
    int wave = t >> 6, lane = t & 63;
    int kh = wave & 1;
    int rh = wave >> 1;
    int col0 = cb * 512 + lane * 4;

    __shared__ float lds[8192];
    float (*xaT)[16] = (float(*)[16])lds;

    const float* xcb = xc + (size_t)br * 1048576;
    const float* lt  = linT + (size_t)br * 262144;
    {
        int kb8 = (t >> 3) * 8;
        int r2  = (t & 7) * 2;
        float4 sc0 = *(const float4*)&sc[br * 512 + kb8];
        float4 sc1 = *(const float4*)&sc[br * 512 + kb8 + 4];
        float4 sh0 = *(const float4*)&sc[br * 512 + 256 + kb8];
        float4 sh1 = *(const float4*)&sc[br * 512 + 256 + kb8 + 4];
        float4 ca0 = *(const float4*)&xcb[(n0 + r2) * 256 + kb8];
        float4 ca1 = *(const float4*)&xcb[(n0 + r2) * 256 + kb8 + 4];
        float4 cb0 = *(const float4*)&xcb[(n0 + r2 + 1) * 256 + kb8];
        float4 cb1 = *(const float4*)&xcb[(n0 + r2 + 1) * 256 + kb8 + 4];
#pragma unroll
        for (int j = 0; j < 8; ++j) {
            float scl = j < 4 ? (&sc0.x)[j] : (&sc1.x)[j - 4];
            float shf = j < 4 ? (&sh0.x)[j] : (&sh1.x)[j - 4];
            float c0  = j < 4 ? (&ca0.x)[j] : (&ca1.x)[j - 4];
            float c1  = j < 4 ? (&cb0.x)[j] : (&cb1.x)[j - 4];
            float z0 = fmaf(c0, scl, shf);
            float z1 = fmaf(c1, scl, shf);
            float2 gw;
            gw.x = 0.5f * z0 * (1.f + erff(z0 * 0.70710678f));
            gw.y = 0.5f * z1 * (1.f + erff(z1 * 0.70710678f));
            *(float2*)&xaT[kb8 + j][r2] = gw;
        }
    }
    __syncthreads();

    float4 accA[2][4];
    float4 accB[2][4];
#pragma unroll
    for (int a = 0; a < 2; ++a)
#pragma unroll
        for (int i = 0; i < 4; ++i) {
            accA[a][i] = make_float4(0.f, 0.f, 0.f, 0.f);
            accB[a][i] = make_float4(0.f, 0.f, 0.f, 0.f);
        }
    int kbeg = kh * 128;
    float4 wA0 = *(const float4*)&lt[(size_t)kbeg * 1024 + col0];
    float4 wB0 = *(const float4*)&lt[(size_t)kbeg * 1024 + col0 + 256];
    float4 a00 = *(const float4*)&xaT[kbeg][8 * rh];
    float4 a10 = *(const float4*)&xaT[kbeg][8 * rh + 4];
    for (int k = kbeg; k < kbeg + 128; k += 2) {
        int kp1 = k + 1;
        float4 wA1 = *(const float4*)&lt[(size_t)kp1 * 1024 + col0];
        float4 wB1 = *(const float4*)&lt[(size_t)kp1 * 1024 + col0 + 256];
        float4 a01 = *(const float4*)&xaT[kp1][8 * rh];
        float4 a11 = *(const float4*)&xaT[kp1][8 * rh + 4];
        FMA_BLOCK(a00, a10, wA0, wB0);
        int kp2 = ((k + 2 - kbeg) & 127) + kbeg;
        wA0 = *(const float4*)&lt[(size_t)kp2 * 1024 + col0];
        wB0 = *(const float4*)&lt[(size_t)kp2 * 1024 + col0 + 256];
        a00 = *(const float4*)&xaT[kp2][8 * rh];
        a10 = *(const float4*)&xaT[kp2][8 * rh + 4];
        FMA_BLOCK(a01, a11, wA1, wB1);
    }
    __syncthreads();
    if (kh == 1) {
        float* dst = &lds[rh * 4096];
#pragma unroll
        for (int a = 0; a < 2; ++a)
#pragma unroll
            for (int i = 0; i < 4; ++i) {
                *(float4*)&dst[(a * 4 + i) * 256 + lane * 4]     = accA[a][i];
                *(float4*)&dst[(8 + a * 4 + i) * 256 + lane * 4] = accB[a][i];
            }
    }
    __syncthreads();
    if (kh == 0) {
        const float* src = &lds[rh * 4096];
#pragma unroll
        for (int a = 0; a < 2; ++a)
#pragma unroll
            for (int i = 0; i < 4; ++i) {
                float4 pA = *(const float4*)&src[(a * 4 + i) * 256 + lane * 4];
                float4 pB = *(const float4*)&src[(8 + a * 4 + i) * 256 + lane * 4];
                accA[a][i].x += pA.x; accA[a][i].y += pA.y;
                accA[a][i].z += pA.z; accA[a][i].w += pA.w;
                accB[a][i].x += pB.x; accB[a][i].y += pB.y;
                accB[a][i].z += pB.z; accB[a][i].w += pB.w;
            }
        const float* lb = br ? si_lb : so_lb;
        float4 lbA = *(const float4*)&lb[col0];
        float4 lbB = *(const float4*)&lb[col0 + 256];
        float* lg = logits + ((size_t)br * 4096 + n0) * 1024;
#pragma unroll
        for (int a = 0; a < 2; ++a)
#pragma unroll
            for (int ri = 0; ri < 4; ++ri) {
                int row = 8 * rh + 4 * a + ri;
                float4 vA, vB;
                vA.x = (&accA[a][0].x)[ri] + lbA.x;
                vA.y = (&accA[a][1].x)[ri] + lbA.y;
                vA.z = (&accA[a][2].x)[ri] + lbA.z;
                vA.w = (&accA[a][3].x)[ri] + lbA.w;
                vB.x = (&accB[a][0].x)[ri] + lbB.x;
                vB.y = (&accB[a][1].x)[ri] + lbB.y;
                vB.z = (&accB[a][2].x)[ri] + lbB.z;
                vB.w = (&accB[a][3].x)[ri] + lbB.w;
                *(float4*)&lg[(size_t)row * 1024 + col0]       = vA;
                *(float4*)&lg[(size_t)row * 1024 + col0 + 256] = vB;
            }
    }
}

// ---------------- softmax stats + exact top-32 per row-branch ----------------
// One wave per row-branch. If split: v = p0 + p1 + bias (fused k-half reduce).
// 3-level radix-histogram select, boundary resolved with full 64-bit
// (key, ~idx) ordering -> selected SET exactly matches jax.lax.top_k.
__global__ __launch_bounds__(256) void topk_k(const float* __restrict__ p0,
                                              const float* __restrict__ p1,
                                              const float* __restrict__ lbso,
                                              const float* __restrict__ lbsi,
                                              int split,
                                              unsigned int* __restrict__ tidx,
                                              float* __restrict__ tval) {
    __shared__ unsigned int hist[4][256];
    __shared__ unsigned int wcnt[4];
    int wave = threadIdx.x >> 6, lane = threadIdx.x & 63;
    int rb = blockIdx.x * 4 + wave;  // 0..8191
    unsigned int* h = hist[wave];

    const float4* lg0 = (const float4*)(p0 + (size_t)rb * 1024);
    float v[16];
    if (split) {
        const float4* lg1 = (const float4*)(p1 + (size_t)rb * 1024);
        const float4* lb4 = (const float4*)(rb < 4096 ? lbso : lbsi);
#pragma unroll
        for (int q = 0; q < 4; ++q) {
            float4 f = lg0[q * 64 + lane];
            float4 g = lg1[q * 64 + lane];
            float4 b = lb4[q * 64 + lane];
            v[q * 4 + 0] = f.x + g.x + b.x;
            v[q * 4 + 1] = f.y + g.y + b.y;
            v[q * 4 + 2] = f.z + g.z + b.z;
            v[q * 4 + 3] = f.w + g.w + b.w;
        }
    } else {
#pragma unroll
        for (int q = 0; q < 4; ++q) {
            float4 f = lg0[q * 64 + lane];
            v[q * 4 + 0] = f.x; v[q * 4 + 1] = f.y;
            v[q * 4 + 2] = f.z; v[q * 4 + 3] = f.w;
        }
    }
    // row max
    float rmax = v[0];
#pragma unroll
    for (int i = 1; i < 16; ++i) rmax = fmaxf(rmax, v[i]);
#pragma unroll
    for (int s = 32; s; s >>= 1) rmax = fmaxf(rmax, __shfl_xor(rmax, s));
    // softmax denominator
    float rsum = 0.f;
#pragma unroll
    for (int i = 0; i < 16; ++i) rsum += __expf(v[i] - rmax);
#pragma unroll
    for (int s = 32; s; s >>= 1) rsum += __shfl_xor(rsum, s);

    unsigned int kb[16];
#pragma unroll
    for (int i = 0; i < 16; ++i) kb[i] = ford(v[i]);

    // --- 3-level radix descent: find 24-bit prefix of the 32nd-largest key ---
    unsigned inmask = 0xFFFFu;
    unsigned need = 32, prefix = 0, lasth = 0;
#pragma unroll
    for (int level = 0; level < 3; ++level) {
        int shift = 24 - level * 8;
        ((uint4*)h)[lane] = make_uint4(0u, 0u, 0u, 0u);
        __syncthreads();
#pragma unroll
        for (int i = 0; i < 16; ++i)
            if ((inmask >> i) & 1u) atomicAdd(&h[(kb[i] >> shift) & 0xFFu], 1u);
        __syncthreads();
        uint4 hv = ((const uint4*)h)[lane];
        unsigned sl = hv.x + hv.y + hv.z + hv.w;
        unsigned S = sl;
#pragma unroll
        for (int off = 1; off < 64; off <<= 1) {
            unsigned o = __shfl_down(S, off);
            if (lane + off < 64) S += o;
        }
        unsigned above = S - sl;
        unsigned cg3 = above + hv.w;
        unsigned cg2 = cg3 + hv.z;
        unsigned cg1 = cg2 + hv.y;
        unsigned cg0 = cg1 + hv.x;
        unsigned pack = 0;
        if      (cg3 >= need) pack = ((4u * lane + 3u) << 12) | cg3;
        else if (cg2 >= need) pack = ((4u * lane + 2u) << 12) | cg2;
        else if (cg1 >= need) pack = ((4u * lane + 1u) << 12) | cg1;
        else if (cg0 >= need) pack = ((4u * lane + 0u) << 12) | cg0;
#pragma unroll
        for (int s = 32; s; s >>= 1) {
            unsigned o = __shfl_xor(pack, s);
            pack = o > pack ? o : pack;
        }
        unsigned bstar = pack >> 12, cstar = pack & 0xFFFu;
        unsigned hstar = h[bstar];
        need -= (cstar - hstar);
        prefix = (prefix << 8) | bstar;
        lasth = hstar;
        unsigned nm = 0;
#pragma unroll
        for (int i = 0; i < 16; ++i)
            if (((inmask >> i) & 1u) && ((kb[i] >> shift) & 0xFFu) == bstar)
                nm |= 1u << i;
        inmask = nm;
        __syncthreads();
    }

    unsigned winmask = 0;
    if (lasth == need) {
        winmask = inmask;
    } else {
        unsigned avail = inmask;
        unsigned long long best = 0ULL;
#pragma unroll
        for (int i = 0; i < 16; ++i)
            if ((avail >> i) & 1u) {
                int j = (i >> 2) * 256 + lane * 4 + (i & 3);
                unsigned long long k64 =
                    ((unsigned long long)kb[i] << 32) | (unsigned int)(~j);
                best = k64 > best ? k64 : best;
            }
        for (unsigned k = 0; k < need; ++k) {
            unsigned long long w = best;
#pragma unroll
            for (int s = 32; s; s >>= 1) {
                unsigned long long o = __shfl_xor(w, s);
                if (o > w) w = o;
            }
            if (best == w) {
                unsigned long long nb = 0ULL;
#pragma unroll
                for (int i = 0; i < 16; ++i)
                    if ((avail >> i) & 1u) {
                        int j = (i >> 2) * 256 + lane * 4 + (i & 3);
                        unsigned long long k64 =
                            ((unsigned long long)kb[i] << 32) | (unsigned int)(~j);
                        if (k64 == w) { winmask |= 1u << i; avail &= ~(1u << i); }
                        else nb = k64 > nb ? k64 : nb;
                    }
                best = nb;
            }
        }
    }

    if (lane == 0) wcnt[wave] = 0;
#pragma unroll
    for (int i = 0; i < 16; ++i) {
        bool wn = ((kb[i] >> 8) > prefix) || ((winmask >> i) & 1u);
        if (wn) {
            unsigned slot = atomicAdd(&wcnt[wave], 1u);
            int j = (i >> 2) * 256 + lane * 4 + (i & 3);
            tidx[(size_t)rb * 32 + slot] = (unsigned int)j;
            tval[(size_t)rb * 32 + slot] = __expf(v[i] - rmax) / rsum;
        }
    }
}

// ---------------- final: out = scatter(sov * x.wT[soi]) + sum_k siv_k*x_c*W[c,:] + bias
__global__ __launch_bounds__(256) void final_k(
    const float* __restrict__ x, const float* __restrict__ W,
    const float* __restrict__ wT, const float* __restrict__ bias,
    const unsigned int* __restrict__ tidx, const float* __restrict__ tval,
    float* __restrict__ out) {
    int n = blockIdx.x, t = threadIdx.x, wave = t >> 6, lane = t & 63;
    __shared__ float xr[1024];
    __shared__ float dres[32];
    __shared__ unsigned int gidx[32]; __shared__ float gval[32];
    __shared__ unsigned int iidx[32]; __shared__ float ival[32];

    ((float4*)xr)[t] = ((const float4*)(x + (size_t)n * 1024))[t];
    if (t < 32) {
        gidx[t] = tidx[(size_t)n * 32 + t];
        gval[t] = tval[(size_t)n * 32 + t];
    } else if (t < 64) {
        int k = t - 32;
        iidx[k] = tidx[((size_t)4096 + n) * 32 + k];
        ival[k] = tval[((size_t)4096 + n) * 32 + k];
    }
    __syncthreads();  // B1

    if (t < 32) ival[t] *= xr[iidx[t]];  // g_k = s_v_in * x[c_k]

    const float4* xr4 = (const float4*)xr;
#pragma unroll
    for (int d8 = 0; d8 < 8; ++d8) {
        int d = wave * 8 + d8;
        const float4* wrow = (const float4*)(wT + (size_t)gidx[d] * 1024);
        float s = 0.f;
#pragma unroll
        for (int q = 0; q < 4; ++q) {
            float4 a = wrow[q * 64 + lane];
            float4 b = xr4[q * 64 + lane];
            s += a.x * b.x + a.y * b.y + a.z * b.z + a.w * b.w;
        }
#pragma unroll
        for (int sft = 32; sft; sft >>= 1) s += __shfl_xor(s, sft);
        if (lane == 0) dres[d] = s * gval[d];
    }
    __syncthreads();  // B2

    float4 acc = ((const float4*)bias)[t];
    for (int k = 0; k < 32; ++k) {
        float g = ival[k];
        unsigned int c = iidx[k];
        float4 wr = ((const float4*)(W + (size_t)c * 1024))[t];
        acc.x = fmaf(g, wr.x, acc.x); acc.y = fmaf(g, wr.y, acc.y);
        acc.z = fmaf(g, wr.z, acc.z); acc.w = fmaf(g, wr.w, acc.w);
    }
    ((float4*)xr)[t] = acc;
    __syncthreads();  // B3
    if (t < 32) xr[gidx[t]] += dres[t];
    __syncthreads();  // B4
    ((float4*)(out + (size_t)n * 1024))[t] = ((float4*)xr)[t];
}

extern "C" void kernel_launch(void* const* d_in, const int* in_sizes, int n_in,
                              void* d_out, int out_size, void* d_ws, size_t ws_size,
                              hipStream_t stream) {
    (void)in_sizes; (void)n_in; (void)out_size;
    const float* x        = (const float*)d_in[0];
    const float* W        = (const float*)d_in[1];
    const float* bias     = (const float*)d_in[2];
    const float* so_cw    = (const float*)d_in[3];
    const float* so_cb    = (const float*)d_in[4];
    const float* so_gm    = (const float*)d_in[5];
    const float* so_bt    = (const float*)d_in[6];
    const float* so_lw    = (const float*)d_in[7];
    const float* so_lb    = (const float*)d_in[8];
    const float* si_cw    = (const float*)d_in[9];
    const float* si_cb    = (const float*)d_in[10];
    const float* si_gm    = (const float*)d_in[11];
    const float* si_bt    = (const float*)d_in[12];
    const float* si_lw    = (const float*)d_in[13];
    const float* si_lb    = (const float*)d_in[14];
    float* out = (float*)d_out;

    float* ws       = (float*)d_ws;
    float* wT       = ws;                       // 1048576
    float* linT     = ws + 1048576;             // 2 x 262144
    float* xc       = ws + 1572864;             // 2 x 1048576
    float* partials = ws + 3670016;             // 262144
    float* sc       = ws + 3932160;             // 1024
    float* p0       = ws + 3933184;             // 8388608
    unsigned int* tidx = (unsigned int*)(ws + 12321792);  // 262144
    float* tval     = ws + 12583936;            // 262144
    float* p1       = ws + 12846080;            // 8388608 (split path only)

    int split = (ws_size >= (size_t)(12846080 + 8388608) * 4) ? 1 : 0;

    transpose_k<<<dim3(32, 32), dim3(32, 8), 0, stream>>>(W, wT, 1024, 1024);
    transpose_k<<<dim3(8, 32), dim3(32, 8), 0, stream>>>(so_lw, linT, 1024, 256);
    transpose_k<<<dim3(8, 32), dim3(32, 8), 0, stream>>>(si_lw, linT + 262144, 1024, 256);
    conv_stats_k<<<256, 256, 0, stream>>>(x, so_cw, so_cb, si_cw, si_cb, xc, partials);
    stats_k<<<2, 256, 0, stream>>>(partials, so_gm, so_bt, si_gm, si_bt, sc);
    if (split) {
        logits_split_k<<<dim3(256, 2, 2), 256, 0, stream>>>(xc, sc, linT, p0, p1);
    } else {
        logits_full_k<<<dim3(256, 2, 2), 256, 0, stream>>>(xc, sc, linT, so_lb, si_lb, p0);
    }
    topk_k<<<2048, 256, 0, stream>>>(p0, p1, so_lb, si_lb, split, tidx, tval);
    final_k<<<4096, 256, 0, stream>>>(x, W, wT, bias, tidx, tval, out);
}

// Round 8
// 169.442 us; speedup vs baseline: 1.0377x; 1.0377x over previous
//
#include <hip/hip_runtime.h>
#include <math.h>

// Problem: B=4, L=1024, C1=1024, C2=1024, K=32, K_IN=32, g=256.
// N = B*L = 4096 rows. All f32.
//
// ws layout (floats):
//   wT      [1024*1024]            off 0
//   linT    [2][256*1024]          off 1048576
//   xc      [2][4096*256]          off 1572864
//   partials[256][4][256]          off 3670016
//   sc      [2][2][256]            off 3932160
//   logits  [8192][1024]           off 3933184
//   tidx    [8192][32] (u32)       off 12321792
//   tval    [8192][32]             off 12583936
// total ~12.85M floats = 51.4 MB

__device__ __forceinline__ unsigned int ford(float f) {
    unsigned int b = __float_as_uint(f);
    return (b & 0x80000000u) ? ~b : (b | 0x80000000u);
}

// ---------------- generic 32x32 tiled transpose: in (R,C) -> out (C,R) -------
__global__ __launch_bounds__(256) void transpose_k(const float* __restrict__ in,
                                                   float* __restrict__ out,
                                                   int R, int C) {
    __shared__ float tile[32][33];
    int c0 = blockIdx.x * 32, r0 = blockIdx.y * 32;
    int tx = threadIdx.x, ty = threadIdx.y;  // block (32,8)
#pragma unroll
    for (int i = 0; i < 32; i += 8)
        tile[ty + i][tx] = in[(size_t)(r0 + ty + i) * C + c0 + tx];
    __syncthreads();
#pragma unroll
    for (int i = 0; i < 32; i += 8)
        out[(size_t)(c0 + ty + i) * R + r0 + tx] = tile[tx][ty + i];
}

// ---------------- grouped 1x1 conv (4->1) for both branches + partial stats --
__global__ __launch_bounds__(256) void conv_stats_k(
    const float* __restrict__ x,
    const float* __restrict__ so_w, const float* __restrict__ so_b,
    const float* __restrict__ si_w, const float* __restrict__ si_b,
    float* __restrict__ xc, float* __restrict__ partials) {
    int g = threadIdx.x;          // channel 0..255
    int n0 = blockIdx.x * 16;     // 256 blocks x 16 rows
    float4 wo = ((const float4*)so_w)[g]; float bo = so_b[g];
    float4 wi = ((const float4*)si_w)[g]; float bi = si_b[g];
    float so_s = 0.f, so_q = 0.f, si_s = 0.f, si_q = 0.f;
#pragma unroll
    for (int r = 0; r < 16; ++r) {
        int n = n0 + r;
        float4 xv = ((const float4*)x)[n * 256 + g];
        float co = fmaf(xv.x, wo.x, fmaf(xv.y, wo.y, fmaf(xv.z, wo.z, fmaf(xv.w, wo.w, bo))));
        float ci = fmaf(xv.x, wi.x, fmaf(xv.y, wi.y, fmaf(xv.z, wi.z, fmaf(xv.w, wi.w, bi))));
        xc[n * 256 + g] = co;
        xc[1048576 + n * 256 + g] = ci;
        so_s += co; so_q += co * co;
        si_s += ci; si_q += ci * ci;
    }
    int b = blockIdx.x;
    partials[(b * 4 + 0) * 256 + g] = so_s;
    partials[(b * 4 + 1) * 256 + g] = so_q;
    partials[(b * 4 + 2) * 256 + g] = si_s;
    partials[(b * 4 + 3) * 256 + g] = si_q;
}

// ---------------- finalize BN stats -> per-channel scale/shift ---------------
__global__ __launch_bounds__(256) void stats_k(
    const float* __restrict__ partials,
    const float* __restrict__ g_so, const float* __restrict__ b_so,
    const float* __restrict__ g_si, const float* __restrict__ b_si,
    float* __restrict__ sc) {
    int g = threadIdx.x;
    int br = blockIdx.x;  // 0 = so, 1 = si
    float s = 0.f, q = 0.f;
    for (int b = 0; b < 256; ++b) {
        s += partials[(b * 4 + br * 2 + 0) * 256 + g];
        q += partials[(b * 4 + br * 2 + 1) * 256 + g];
    }
    float mean = s * (1.f / 4096.f);
    float var  = q * (1.f / 4096.f) - mean * mean;  // biased, matches ref
    float rstd = rsqrtf(var + 1e-5f);
    float gm = br ? g_si[g] : g_so[g];
    float bt = br ? b_si[g] : b_so[g];
    float scale = gm * rstd;
    sc[br * 512 + g]       = scale;
    sc[br * 512 + 256 + g] = fmaf(-mean, scale, bt);
}

#define FMA_BLOCK(A0, A1, WA, WB)                                   \
    {                                                               \
        _Pragma("unroll")                                           \
        for (int i = 0; i < 4; ++i) {                               \
            float wa = (&WA.x)[i], wb = (&WB.x)[i];                 \
            accA[0][i].x = fmaf(A0.x, wa, accA[0][i].x);            \
            accA[0][i].y = fmaf(A0.y, wa, accA[0][i].y);            \
            accA[0][i].z = fmaf(A0.z, wa, accA[0][i].z);            \
            accA[0][i].w = fmaf(A0.w, wa, accA[0][i].w);            \
            accA[1][i].x = fmaf(A1.x, wa, accA[1][i].x);            \
            accA[1][i].y = fmaf(A1.y, wa, accA[1][i].y);            \
            accA[1][i].z = fmaf(A1.z, wa, accA[1][i].z);            \
            accA[1][i].w = fmaf(A1.w, wa, accA[1][i].w);            \
            accB[0][i].x = fmaf(A0.x, wb, accB[0][i].x);            \
            accB[0][i].y = fmaf(A0.y, wb, accB[0][i].y);            \
            accB[0][i].z = fmaf(A0.z, wb, accB[0][i].z);            \
            accB[0][i].w = fmaf(A0.w, wb, accB[0][i].w);            \
            accB[1][i].x = fmaf(A1.x, wb, accB[1][i].x);            \
            accB[1][i].y = fmaf(A1.y, wb, accB[1][i].y);            \
            accB[1][i].z = fmaf(A1.z, wb, accB[1][i].z);            \
            accB[1][i].w = fmaf(A1.w, wb, accB[1][i].w);            \
        }                                                           \
    }

// ---------------- BN+GELU fused + (4096x256)@(256x1024) f32 GEMM -------------
// Block = 16 rows x 512 cols, 4 waves = (row-half x k-half), in-block split-K
// reduce via LDS. Key fix this round: PAIR-granularity ping-pong prefetch --
// all loads for ks (k+2,k+3) are issued BEFORE the 128-FMA-inst block for
// (k,k+1), giving 256 cy issue-to-use distance (>= L2 latency ~200-300 cy).
// Pointer-bump addressing keeps non-FMA VALU ~6%.
__global__ __launch_bounds__(256, 3) void logits_k(
    const float* __restrict__ xc, const float* __restrict__ sc,
    const float* __restrict__ linT,
    const float* __restrict__ so_lb, const float* __restrict__ si_lb,
    float* __restrict__ logits) {
    int t = threadIdx.x;
    int n0 = blockIdx.x * 16;
    int cb = blockIdx.y;
    int br = blockIdx.z;
    int wave = t >> 6, lane = t & 63;
    int kh = wave & 1;
    int rh = wave >> 1;
    int col0 = cb * 512 + lane * 4;

    __shared__ float lds[8448];         // 33 KB: xaT[258][16] pad; reduce buf reuse
    float (*xaT)[16] = (float(*)[16])lds;

    const float* xcb = xc + (size_t)br * 1048576;
    const float* lt  = linT + (size_t)br * 262144;

    // ---- stage ALL of xa^T (BN + exact GELU): 2 rows x 8 k per thread ----
    {
        int kb8 = (t >> 3) * 8;
        int r2  = (t & 7) * 2;
        float4 sc0 = *(const float4*)&sc[br * 512 + kb8];
        float4 sc1 = *(const float4*)&sc[br * 512 + kb8 + 4];
        float4 sh0 = *(const float4*)&sc[br * 512 + 256 + kb8];
        float4 sh1 = *(const float4*)&sc[br * 512 + 256 + kb8 + 4];
        float4 ca0 = *(const float4*)&xcb[(n0 + r2) * 256 + kb8];
        float4 ca1 = *(const float4*)&xcb[(n0 + r2) * 256 + kb8 + 4];
        float4 cb0 = *(const float4*)&xcb[(n0 + r2 + 1) * 256 + kb8];
        float4 cb1 = *(const float4*)&xcb[(n0 + r2 + 1) * 256 + kb8 + 4];
#pragma unroll
        for (int j = 0; j < 8; ++j) {
            float scl = j < 4 ? (&sc0.x)[j] : (&sc1.x)[j - 4];
            float shf = j < 4 ? (&sh0.x)[j] : (&sh1.x)[j - 4];
            float c0  = j < 4 ? (&ca0.x)[j] : (&ca1.x)[j - 4];
            float c1  = j < 4 ? (&cb0.x)[j] : (&cb1.x)[j - 4];
            float z0 = fmaf(c0, scl, shf);
            float z1 = fmaf(c1, scl, shf);
            float2 gw;
            gw.x = 0.5f * z0 * (1.f + erff(z0 * 0.70710678f));
            gw.y = 0.5f * z1 * (1.f + erff(z1 * 0.70710678f));
            *(float2*)&xaT[kb8 + j][r2] = gw;
        }
    }
    __syncthreads();

    float4 accA[2][4];
    float4 accB[2][4];
#pragma unroll
    for (int a = 0; a < 2; ++a)
#pragma unroll
        for (int i = 0; i < 4; ++i) {
            accA[a][i] = make_float4(0.f, 0.f, 0.f, 0.f);
            accB[a][i] = make_float4(0.f, 0.f, 0.f, 0.f);
        }

    // ---- 128-k loop (this wave's k half), pair ping-pong, pointer bump ----
    // Dangling prefetch reads 2 k past the half: xaT has 2 pad rows; global
    // pointer stays inside ws (next linT half / xc) -- harmless.
    int kbeg = kh * 128;
    const float* wp  = lt + (size_t)kbeg * 1024 + col0;
    const float* xab = &xaT[kbeg][8 * rh];
    float4 wA0 = *(const float4*)wp;
    float4 wB0 = *(const float4*)(wp + 256);
    float4 wA1 = *(const float4*)(wp + 1024);
    float4 wB1 = *(const float4*)(wp + 1280);
    float4 a00 = *(const float4*)xab;
    float4 a10 = *(const float4*)(xab + 4);
    float4 a01 = *(const float4*)(xab + 16);
    float4 a11 = *(const float4*)(xab + 20);
#pragma unroll 2
    for (int k = 0; k < 128; k += 2) {
        // prefetch pair (k+2, k+3) -- issued 128 FMA insts (256 cy) before use
        float4 pA0 = *(const float4*)(wp + 2048);
        float4 pB0 = *(const float4*)(wp + 2304);
        float4 pA1 = *(const float4*)(wp + 3072);
        float4 pB1 = *(const float4*)(wp + 3328);
        float4 qa0 = *(const float4*)(xab + 32);
        float4 qa1 = *(const float4*)(xab + 36);
        float4 qb0 = *(const float4*)(xab + 48);
        float4 qb1 = *(const float4*)(xab + 52);
        FMA_BLOCK(a00, a10, wA0, wB0);
        FMA_BLOCK(a01, a11, wA1, wB1);
        wA0 = pA0; wB0 = pB0; wA1 = pA1; wB1 = pB1;
        a00 = qa0; a10 = qa1; a01 = qb0; a11 = qb1;
        wp += 2048;
        xab += 32;
    }

    // ---- split-K reduction: kh=1 waves dump, kh=0 waves add + write out ----
    __syncthreads();  // all xaT reads done; lds reusable
    if (kh == 1) {
        float* dst = &lds[rh * 4096];   // [16 slots][256 floats]
#pragma unroll
        for (int a = 0; a < 2; ++a)
#pragma unroll
            for (int i = 0; i < 4; ++i) {
                *(float4*)&dst[(a * 4 + i) * 256 + lane * 4]     = accA[a][i];
                *(float4*)&dst[(8 + a * 4 + i) * 256 + lane * 4] = accB[a][i];
            }
    }
    __syncthreads();
    if (kh == 0) {
        const float* src = &lds[rh * 4096];
#pragma unroll
        for (int a = 0; a < 2; ++a)
#pragma unroll
            for (int i = 0; i < 4; ++i) {
                float4 pA = *(const float4*)&src[(a * 4 + i) * 256 + lane * 4];
                float4 pB = *(const float4*)&src[(8 + a * 4 + i) * 256 + lane * 4];
                accA[a][i].x += pA.x; accA[a][i].y += pA.y;
                accA[a][i].z += pA.z; accA[a][i].w += pA.w;
                accB[a][i].x += pB.x; accB[a][i].y += pB.y;
                accB[a][i].z += pB.z; accB[a][i].w += pB.w;
            }
        const float* lb = br ? si_lb : so_lb;
        float4 lbA = *(const float4*)&lb[col0];
        float4 lbB = *(const float4*)&lb[col0 + 256];
        float* lg = logits + ((size_t)br * 4096 + n0) * 1024;
#pragma unroll
        for (int a = 0; a < 2; ++a)
#pragma unroll
            for (int ri = 0; ri < 4; ++ri) {
                int row = 8 * rh + 4 * a + ri;
                float4 vA, vB;
                vA.x = (&accA[a][0].x)[ri] + lbA.x;
                vA.y = (&accA[a][1].x)[ri] + lbA.y;
                vA.z = (&accA[a][2].x)[ri] + lbA.z;
                vA.w = (&accA[a][3].x)[ri] + lbA.w;
                vB.x = (&accB[a][0].x)[ri] + lbB.x;
                vB.y = (&accB[a][1].x)[ri] + lbB.y;
                vB.z = (&accB[a][2].x)[ri] + lbB.z;
                vB.w = (&accB[a][3].x)[ri] + lbB.w;
                *(float4*)&lg[(size_t)row * 1024 + col0]       = vA;
                *(float4*)&lg[(size_t)row * 1024 + col0 + 256] = vB;
            }
    }
}

// ---------------- softmax stats + exact top-32 per row-branch ----------------
// One wave per row-branch. 3-level radix-histogram select on the orderable key
// (8 bits/level, 24 bits total), boundary resolved with full 64-bit (key,~idx)
// ordering -> selected SET exactly matches jax.lax.top_k (ties -> lowest idx).
__global__ __launch_bounds__(256) void topk_k(const float* __restrict__ logits,
                                              unsigned int* __restrict__ tidx,
                                              float* __restrict__ tval) {
    __shared__ unsigned int hist[4][256];
    __shared__ unsigned int wcnt[4];
    int wave = threadIdx.x >> 6, lane = threadIdx.x & 63;
    int rb = blockIdx.x * 4 + wave;  // 0..8191
    unsigned int* h = hist[wave];

    const float4* lg = (const float4*)(logits + (size_t)rb * 1024);
    float v[16];
#pragma unroll
    for (int q = 0; q < 4; ++q) {
        float4 f = lg[q * 64 + lane];
        v[q * 4 + 0] = f.x; v[q * 4 + 1] = f.y;
        v[q * 4 + 2] = f.z; v[q * 4 + 3] = f.w;
    }
    // row max
    float rmax = v[0];
#pragma unroll
    for (int i = 1; i < 16; ++i) rmax = fmaxf(rmax, v[i]);
#pragma unroll
    for (int s = 32; s; s >>= 1) rmax = fmaxf(rmax, __shfl_xor(rmax, s));
    // softmax denominator
    float rsum = 0.f;
#pragma unroll
    for (int i = 0; i < 16; ++i) rsum += __expf(v[i] - rmax);
#pragma unroll
    for (int s = 32; s; s >>= 1) rsum += __shfl_xor(rsum, s);

    unsigned int kb[16];
#pragma unroll
    for (int i = 0; i < 16; ++i) kb[i] = ford(v[i]);

    unsigned inmask = 0xFFFFu;
    unsigned need = 32, prefix = 0, lasth = 0;
#pragma unroll
    for (int level = 0; level < 3; ++level) {
        int shift = 24 - level * 8;
        ((uint4*)h)[lane] = make_uint4(0u, 0u, 0u, 0u);
        __syncthreads();
#pragma unroll
        for (int i = 0; i < 16; ++i)
            if ((inmask >> i) & 1u) atomicAdd(&h[(kb[i] >> shift) & 0xFFu], 1u);
        __syncthreads();
        uint4 hv = ((const uint4*)h)[lane];
        unsigned sl = hv.x + hv.y + hv.z + hv.w;
        unsigned S = sl;
#pragma unroll
        for (int off = 1; off < 64; off <<= 1) {
            unsigned o = __shfl_down(S, off);
            if (lane + off < 64) S += o;
        }
        unsigned above = S - sl;
        unsigned cg3 = above + hv.w;
        unsigned cg2 = cg3 + hv.z;
        unsigned cg1 = cg2 + hv.y;
        unsigned cg0 = cg1 + hv.x;
        unsigned pack = 0;
        if      (cg3 >= need) pack = ((4u * lane + 3u) << 12) | cg3;
        else if (cg2 >= need) pack = ((4u * lane + 2u) << 12) | cg2;
        else if (cg1 >= need) pack = ((4u * lane + 1u) << 12) | cg1;
        else if (cg0 >= need) pack = ((4u * lane + 0u) << 12) | cg0;
#pragma unroll
        for (int s = 32; s; s >>= 1) {
            unsigned o = __shfl_xor(pack, s);
            pack = o > pack ? o : pack;
        }
        unsigned bstar = pack >> 12, cstar = pack & 0xFFFu;
        unsigned hstar = h[bstar];
        need -= (cstar - hstar);
        prefix = (prefix << 8) | bstar;
        lasth = hstar;
        unsigned nm = 0;
#pragma unroll
        for (int i = 0; i < 16; ++i)
            if (((inmask >> i) & 1u) && ((kb[i] >> shift) & 0xFFu) == bstar)
                nm |= 1u << i;
        inmask = nm;
        __syncthreads();
    }

    unsigned winmask = 0;
    if (lasth == need) {
        winmask = inmask;
    } else {
        unsigned avail = inmask;
        unsigned long long best = 0ULL;
#pragma unroll
        for (int i = 0; i < 16; ++i)
            if ((avail >> i) & 1u) {
                int j = (i >> 2) * 256 + lane * 4 + (i & 3);
                unsigned long long k64 =
                    ((unsigned long long)kb[i] << 32) | (unsigned int)(~j);
                best = k64 > best ? k64 : best;
            }
        for (unsigned k = 0; k < need; ++k) {
            unsigned long long w = best;
#pragma unroll
            for (int s = 32; s; s >>= 1) {
                unsigned long long o = __shfl_xor(w, s);
                if (o > w) w = o;
            }
            if (best == w) {
                unsigned long long nb = 0ULL;
#pragma unroll
                for (int i = 0; i < 16; ++i)
                    if ((avail >> i) & 1u) {
                        int j = (i >> 2) * 256 + lane * 4 + (i & 3);
                        unsigned long long k64 =
                            ((unsigned long long)kb[i] << 32) | (unsigned int)(~j);
                        if (k64 == w) { winmask |= 1u << i; avail &= ~(1u << i); }
                        else nb = k64 > nb ? k64 : nb;
                    }
                best = nb;
            }
        }
    }

    if (lane == 0) wcnt[wave] = 0;
#pragma unroll
    for (int i = 0; i < 16; ++i) {
        bool wn = ((kb[i] >> 8) > prefix) || ((winmask >> i) & 1u);
        if (wn) {
            unsigned slot = atomicAdd(&wcnt[wave], 1u);
            int j = (i >> 2) * 256 + lane * 4 + (i & 3);
            tidx[(size_t)rb * 32 + slot] = (unsigned int)j;
            tval[(size_t)rb * 32 + slot] = __expf(v[i] - rmax) / rsum;
        }
    }
}

// ---------------- final: out = scatter(sov * x.wT[soi]) + sum_k siv_k*x_c*W[c,:] + bias
__global__ __launch_bounds__(256) void final_k(
    const float* __restrict__ x, const float* __restrict__ W,
    const float* __restrict__ wT, const float* __restrict__ bias,
    const unsigned int* __restrict__ tidx, const float* __restrict__ tval,
    float* __restrict__ out) {
    int n = blockIdx.x, t = threadIdx.x, wave = t >> 6, lane = t & 63;
    __shared__ float xr[1024];
    __shared__ float dres[32];
    __shared__ unsigned int gidx[32]; __shared__ float gval[32];
    __shared__ unsigned int iidx[32]; __shared__ float ival[32];

    ((float4*)xr)[t] = ((const float4*)(x + (size_t)n * 1024))[t];
    if (t < 32) {
        gidx[t] = tidx[(size_t)n * 32 + t];
        gval[t] = tval[(size_t)n * 32 + t];
    } else if (t < 64) {
        int k = t - 32;
        iidx[k] = tidx[((size_t)4096 + n) * 32 + k];
        ival[k] = tval[((size_t)4096 + n) * 32 + k];
    }
    __syncthreads();  // B1

    if (t < 32) ival[t] *= xr[iidx[t]];  // g_k = s_v_in * x[c_k]

    const float4* xr4 = (const float4*)xr;
#pragma unroll
    for (int d8 = 0; d8 < 8; ++d8) {
        int d = wave * 8 + d8;
        const float4* wrow = (const float4*)(wT + (size_t)gidx[d] * 1024);
        float s = 0.f;
#pragma unroll
        for (int q = 0; q < 4; ++q) {
            float4 a = wrow[q * 64 + lane];
            float4 b = xr4[q * 64 + lane];
            s += a.x * b.x + a.y * b.y + a.z * b.z + a.w * b.w;
        }
#pragma unroll
        for (int sft = 32; sft; sft >>= 1) s += __shfl_xor(s, sft);
        if (lane == 0) dres[d] = s * gval[d];
    }
    __syncthreads();  // B2

    float4 acc = ((const float4*)bias)[t];
    for (int k = 0; k < 32; ++k) {
        float g = ival[k];
        unsigned int c = iidx[k];
        float4 wr = ((const float4*)(W + (size_t)c * 1024))[t];
        acc.x = fmaf(g, wr.x, acc.x); acc.y = fmaf(g, wr.y, acc.y);
        acc.z = fmaf(g, wr.z, acc.z); acc.w = fmaf(g, wr.w, acc.w);
    }
    ((float4*)xr)[t] = acc;
    __syncthreads();  // B3
    if (t < 32) xr[gidx[t]] += dres[t];
    __syncthreads();  // B4
    ((float4*)(out + (size_t)n * 1024))[t] = ((float4*)xr)[t];
}

extern "C" void kernel_launch(void* const* d_in, const int* in_sizes, int n_in,
                              void* d_out, int out_size, void* d_ws, size_t ws_size,
                              hipStream_t stream) {
    (void)in_sizes; (void)n_in; (void)out_size; (void)ws_size;
    const float* x        = (const float*)d_in[0];
    const float* W        = (const float*)d_in[1];
    const float* bias     = (const float*)d_in[2];
    const float* so_cw    = (const float*)d_in[3];
    const float* so_cb    = (const float*)d_in[4];
    const float* so_gm    = (const float*)d_in[5];
    const float* so_bt    = (const float*)d_in[6];
    const float* so_lw    = (const float*)d_in[7];
    const float* so_lb    = (const float*)d_in[8];
    const float* si_cw    = (const float*)d_in[9];
    const float* si_cb    = (const float*)d_in[10];
    const float* si_gm    = (const float*)d_in[11];
    const float* si_bt    = (const float*)d_in[12];
    const float* si_lw    = (const float*)d_in[13];
    const float* si_lb    = (const float*)d_in[14];
    float* out = (float*)d_out;

    float* ws       = (float*)d_ws;
    float* wT       = ws;                       // 1048576
    float* linT     = ws + 1048576;             // 2 x 262144
    float* xc       = ws + 1572864;             // 2 x 1048576
    float* partials = ws + 3670016;             // 262144
    float* sc       = ws + 3932160;             // 1024
    float* logits   = ws + 3933184;             // 8388608
    unsigned int* tidx = (unsigned int*)(ws + 12321792);  // 262144
    float* tval     = ws + 12583936;            // 262144

    transpose_k<<<dim3(32, 32), dim3(32, 8), 0, stream>>>(W, wT, 1024, 1024);
    transpose_k<<<dim3(8, 32), dim3(32, 8), 0, stream>>>(so_lw, linT, 1024, 256);
    transpose_k<<<dim3(8, 32), dim3(32, 8), 0, stream>>>(si_lw, linT + 262144, 1024, 256);
    conv_stats_k<<<256, 256, 0, stream>>>(x, so_cw, so_cb, si_cw, si_cb, xc, partials);
    stats_k<<<2, 256, 0, stream>>>(partials, so_gm, so_bt, si_gm, si_bt, sc);
    logits_k<<<dim3(256, 2, 2), 256, 0, stream>>>(xc, sc, linT, so_lb, si_lb, logits);
    topk_k<<<2048, 256, 0, stream>>>(logits, tidx, tval);
    final_k<<<4096, 256, 0, stream>>>(x, W, wT, bias, tidx, tval, out);
}

// Round 9
// 133.542 us; speedup vs baseline: 1.3167x; 1.2688x over previous
//
#include <hip/hip_runtime.h>
#include <math.h>

// Problem: B=4, L=1024, C1=1024, C2=1024, K=32, K_IN=32, g=256.
// N = B*L = 4096 rows. All f32.
//
// ws layout (floats):
//   wT      [1024*1024]            off 0
//   whl     [524288 f32-equiv]     off 1048576  (bf16 hi/lo split weights, 2MB)
//   xc      [2][4096*256]          off 1572864
//   partials[256][4][256]          off 3670016
//   sc      [2][2][256]            off 3932160
//   logits  [8192][1024]           off 3933184
//   tidx    [8192][32] (u32)       off 12321792
//   tval    [8192][32]             off 12583936
// total ~12.85M floats = 51.4 MB

typedef __attribute__((ext_vector_type(8))) short short8;
typedef __attribute__((ext_vector_type(4))) float f32x4;

__device__ __forceinline__ unsigned int ford(float f) {
    unsigned int b = __float_as_uint(f);
    return (b & 0x80000000u) ? ~b : (b | 0x80000000u);
}

// ---------------- generic 32x32 tiled transpose: in (R,C) -> out (C,R) -------
__global__ __launch_bounds__(256) void transpose_k(const float* __restrict__ in,
                                                   float* __restrict__ out,
                                                   int R, int C) {
    __shared__ float tile[32][33];
    int c0 = blockIdx.x * 32, r0 = blockIdx.y * 32;
    int tx = threadIdx.x, ty = threadIdx.y;  // block (32,8)
#pragma unroll
    for (int i = 0; i < 32; i += 8)
        tile[ty + i][tx] = in[(size_t)(r0 + ty + i) * C + c0 + tx];
    __syncthreads();
#pragma unroll
    for (int i = 0; i < 32; i += 8)
        out[(size_t)(c0 + ty + i) * R + r0 + tx] = tile[tx][ty + i];
}

// ---------------- split lin_w (f32 [1024 col][256 k]) into bf16 hi/lo frags --
// Fragment layout for mfma_f32_16x16x32_bf16 B operand: tile (ct,kt), lane l
// holds col = ct*16 + (l&15), k = kt*32 + (l>>4)*8 + j (j=0..7, 16 B).
// whl index: ((((br*2+h)*64+ct)*8+kt)*64+l)*8 ushorts.
__global__ __launch_bounds__(256) void wsplit_k(
    const float* __restrict__ so_lw, const float* __restrict__ si_lw,
    unsigned short* __restrict__ whl) {
    int g = blockIdx.x * 256 + threadIdx.x;  // 0..65535
    int br = g >> 15;
    int rem = g & 32767;
    int ct = rem >> 9;
    int kt = (rem >> 6) & 7;
    int l  = rem & 63;
    int col = ct * 16 + (l & 15);
    int ks  = kt * 32 + (l >> 4) * 8;
    const float* lw = (br ? si_lw : so_lw) + (size_t)col * 256 + ks;
    float4 v0 = *(const float4*)lw;
    float4 v1 = *(const float4*)(lw + 4);
    unsigned hh[8], ll[8];
#pragma unroll
    for (int j = 0; j < 8; ++j) {
        float a = j < 4 ? (&v0.x)[j] : (&v1.x)[j - 4];
        unsigned b = __float_as_uint(a);
        unsigned rh = (b + 0x7FFFu + ((b >> 16) & 1u)) & 0xFFFF0000u;
        hh[j] = rh >> 16;
        float res = a - __uint_as_float(rh);
        unsigned c = __float_as_uint(res);
        unsigned rl = (c + 0x7FFFu + ((c >> 16) & 1u)) & 0xFFFF0000u;
        ll[j] = rl >> 16;
    }
    uint4 ph, pl;
    ph.x = hh[0] | (hh[1] << 16); ph.y = hh[2] | (hh[3] << 16);
    ph.z = hh[4] | (hh[5] << 16); ph.w = hh[6] | (hh[7] << 16);
    pl.x = ll[0] | (ll[1] << 16); pl.y = ll[2] | (ll[3] << 16);
    pl.z = ll[4] | (ll[5] << 16); pl.w = ll[6] | (ll[7] << 16);
    size_t base = (((((size_t)br * 2 + 0) * 64 + ct) * 8 + kt) * 64 + l) * 8;
    size_t hstride = (size_t)64 * 8 * 64 * 8;  // h=0 -> h=1
    *(uint4*)&whl[base]           = ph;
    *(uint4*)&whl[base + hstride] = pl;
}

// ---------------- grouped 1x1 conv (4->1) for both branches + partial stats --
__global__ __launch_bounds__(256) void conv_stats_k(
    const float* __restrict__ x,
    const float* __restrict__ so_w, const float* __restrict__ so_b,
    const float* __restrict__ si_w, const float* __restrict__ si_b,
    float* __restrict__ xc, float* __restrict__ partials) {
    int g = threadIdx.x;          // channel 0..255
    int n0 = blockIdx.x * 16;     // 256 blocks x 16 rows
    float4 wo = ((const float4*)so_w)[g]; float bo = so_b[g];
    float4 wi = ((const float4*)si_w)[g]; float bi = si_b[g];
    float so_s = 0.f, so_q = 0.f, si_s = 0.f, si_q = 0.f;
#pragma unroll
    for (int r = 0; r < 16; ++r) {
        int n = n0 + r;
        float4 xv = ((const float4*)x)[n * 256 + g];
        float co = fmaf(xv.x, wo.x, fmaf(xv.y, wo.y, fmaf(xv.z, wo.z, fmaf(xv.w, wo.w, bo))));
        float ci = fmaf(xv.x, wi.x, fmaf(xv.y, wi.y, fmaf(xv.z, wi.z, fmaf(xv.w, wi.w, bi))));
        xc[n * 256 + g] = co;
        xc[1048576 + n * 256 + g] = ci;
        so_s += co; so_q += co * co;
        si_s += ci; si_q += ci * ci;
    }
    int b = blockIdx.x;
    partials[(b * 4 + 0) * 256 + g] = so_s;
    partials[(b * 4 + 1) * 256 + g] = so_q;
    partials[(b * 4 + 2) * 256 + g] = si_s;
    partials[(b * 4 + 3) * 256 + g] = si_q;
}

// ---------------- finalize BN stats -> per-channel scale/shift ---------------
__global__ __launch_bounds__(256) void stats_k(
    const float* __restrict__ partials,
    const float* __restrict__ g_so, const float* __restrict__ b_so,
    const float* __restrict__ g_si, const float* __restrict__ b_si,
    float* __restrict__ sc) {
    int g = threadIdx.x;
    int br = blockIdx.x;  // 0 = so, 1 = si
    float s = 0.f, q = 0.f;
    for (int b = 0; b < 256; ++b) {
        s += partials[(b * 4 + br * 2 + 0) * 256 + g];
        q += partials[(b * 4 + br * 2 + 1) * 256 + g];
    }
    float mean = s * (1.f / 4096.f);
    float var  = q * (1.f / 4096.f) - mean * mean;  // biased, matches ref
    float rstd = rsqrtf(var + 1e-5f);
    float gm = br ? g_si[g] : g_so[g];
    float bt = br ? b_si[g] : b_so[g];
    float scale = gm * rstd;
    sc[br * 512 + g]       = scale;
    sc[br * 512 + 256 + g] = fmaf(-mean, scale, bt);
}

// ---------------- BN+GELU fused + bf16x4-split MFMA logits GEMM --------------
// C = xa @ w, xa and w each split into hi+lo bf16; 4 MFMAs reconstruct the
// product of the split values exactly (error = split residual ~2^-18 rel --
// selection-safe vs f32 reference). Block = 64 rows x 256 cols, 4 waves; each
// wave: 4 row-tiles x 4 col-tiles, acc 64 VGPR. xa hi/lo staged in LDS in
// fragment layout (lane-contiguous 16 B => conflict-free ds_read_b128).
__global__ __launch_bounds__(256, 2) void logits_mfma_k(
    const float* __restrict__ xc, const float* __restrict__ sc,
    const unsigned short* __restrict__ whl,
    const float* __restrict__ so_lb, const float* __restrict__ si_lb,
    float* __restrict__ logits) {
    __shared__ unsigned short ah[2048 * 8];  // 32 KB
    __shared__ unsigned short al[2048 * 8];  // 32 KB
    int t = threadIdx.x;
    int n0 = blockIdx.x * 64;
    int cb = blockIdx.y;          // 256-col block
    int br = blockIdx.z;
    int wave = t >> 6, lane = t & 63;

    const float* xcb = xc + (size_t)br * 1048576;
    const float* scp = sc + br * 512;

    // ---- stage xa hi/lo in fragment layout: slot s=(rt,kt,l), 8 elems ----
#pragma unroll
    for (int i = 0; i < 8; ++i) {
        int s = t + 256 * i;
        int rt = s >> 9, kt = (s >> 6) & 7, l = s & 63;
        int row = n0 + rt * 16 + (l & 15);
        int ks = kt * 32 + (l >> 4) * 8;
        const float* xp = xcb + (size_t)row * 256 + ks;
        float4 c0 = *(const float4*)xp;
        float4 c1 = *(const float4*)(xp + 4);
        float4 s0 = *(const float4*)(scp + ks);
        float4 s1 = *(const float4*)(scp + ks + 4);
        float4 h0 = *(const float4*)(scp + 256 + ks);
        float4 h1 = *(const float4*)(scp + 256 + ks + 4);
        unsigned hh[8], ll[8];
#pragma unroll
        for (int j = 0; j < 8; ++j) {
            float cv  = j < 4 ? (&c0.x)[j] : (&c1.x)[j - 4];
            float scl = j < 4 ? (&s0.x)[j] : (&s1.x)[j - 4];
            float shf = j < 4 ? (&h0.x)[j] : (&h1.x)[j - 4];
            float z = fmaf(cv, scl, shf);
            float a = 0.5f * z * (1.f + erff(z * 0.70710678f));
            unsigned b = __float_as_uint(a);
            unsigned rh = (b + 0x7FFFu + ((b >> 16) & 1u)) & 0xFFFF0000u;
            hh[j] = rh >> 16;
            float res = a - __uint_as_float(rh);
            unsigned cc = __float_as_uint(res);
            unsigned rl = (cc + 0x7FFFu + ((cc >> 16) & 1u)) & 0xFFFF0000u;
            ll[j] = rl >> 16;
        }
        uint4 ph, pl;
        ph.x = hh[0] | (hh[1] << 16); ph.y = hh[2] | (hh[3] << 16);
        ph.z = hh[4] | (hh[5] << 16); ph.w = hh[6] | (hh[7] << 16);
        pl.x = ll[0] | (ll[1] << 16); pl.y = ll[2] | (ll[3] << 16);
        pl.z = ll[4] | (ll[5] << 16); pl.w = ll[6] | (ll[7] << 16);
        *(uint4*)&ah[(size_t)s * 8] = ph;
        *(uint4*)&al[(size_t)s * 8] = pl;
    }
    __syncthreads();

    f32x4 acc[4][4];  // [ci][rt]
#pragma unroll
    for (int ci = 0; ci < 4; ++ci)
#pragma unroll
        for (int rt = 0; rt < 4; ++rt) acc[ci][rt] = (f32x4){0.f, 0.f, 0.f, 0.f};

    const size_t hstride = (size_t)64 * 8 * 64 * 8;
#pragma unroll 2
    for (int kt = 0; kt < 8; ++kt) {
        short8 Ah[4], Al[4];
#pragma unroll
        for (int rt = 0; rt < 4; ++rt) {
            Ah[rt] = *(const short8*)&ah[(((rt * 8 + kt) * 64) + lane) * 8];
            Al[rt] = *(const short8*)&al[(((rt * 8 + kt) * 64) + lane) * 8];
        }
#pragma unroll
        for (int ci = 0; ci < 4; ++ci) {
            int ctg = cb * 16 + wave * 4 + ci;
            size_t boff = ((((size_t)br * 2 + 0) * 64 + ctg) * 8 + kt) * 64 * 8 +
                          (size_t)lane * 8;
            short8 Wh = *(const short8*)&whl[boff];
            short8 Wl = *(const short8*)&whl[boff + hstride];
#pragma unroll
            for (int rt = 0; rt < 4; ++rt) {
                acc[ci][rt] = __builtin_amdgcn_mfma_f32_16x16x32_bf16(Ah[rt], Wh, acc[ci][rt], 0, 0, 0);
                acc[ci][rt] = __builtin_amdgcn_mfma_f32_16x16x32_bf16(Ah[rt], Wl, acc[ci][rt], 0, 0, 0);
                acc[ci][rt] = __builtin_amdgcn_mfma_f32_16x16x32_bf16(Al[rt], Wh, acc[ci][rt], 0, 0, 0);
                acc[ci][rt] = __builtin_amdgcn_mfma_f32_16x16x32_bf16(Al[rt], Wl, acc[ci][rt], 0, 0, 0);
            }
        }
    }

    // ---- epilogue: + bias, store f32 logits. C/D: col=lane&15, row=(lane>>4)*4+i
    const float* lb = br ? si_lb : so_lb;
#pragma unroll
    for (int ci = 0; ci < 4; ++ci) {
        int colg = cb * 256 + (wave * 4 + ci) * 16 + (lane & 15);
        float lbv = lb[colg];
#pragma unroll
        for (int rt = 0; rt < 4; ++rt) {
#pragma unroll
            for (int i = 0; i < 4; ++i) {
                int row = n0 + rt * 16 + (lane >> 4) * 4 + i;
                logits[((size_t)br * 4096 + row) * 1024 + colg] = acc[ci][rt][i] + lbv;
            }
        }
    }
}

// ---------------- softmax stats + exact top-32 per row-branch ----------------
// One wave per row-branch. 3-level radix-histogram select on the orderable key
// (8 bits/level), boundary resolved with full 64-bit (key,~idx) ordering ->
// selected SET exactly matches jax.lax.top_k (ties -> lowest idx).
__global__ __launch_bounds__(256) void topk_k(const float* __restrict__ logits,
                                              unsigned int* __restrict__ tidx,
                                              float* __restrict__ tval) {
    __shared__ unsigned int hist[4][256];
    __shared__ unsigned int wcnt[4];
    int wave = threadIdx.x >> 6, lane = threadIdx.x & 63;
    int rb = blockIdx.x * 4 + wave;  // 0..8191
    unsigned int* h = hist[wave];

    const float4* lg = (const float4*)(logits + (size_t)rb * 1024);
    float v[16];
#pragma unroll
    for (int q = 0; q < 4; ++q) {
        float4 f = lg[q * 64 + lane];
        v[q * 4 + 0] = f.x; v[q * 4 + 1] = f.y;
        v[q * 4 + 2] = f.z; v[q * 4 + 3] = f.w;
    }
    // row max
    float rmax = v[0];
#pragma unroll
    for (int i = 1; i < 16; ++i) rmax = fmaxf(rmax, v[i]);
#pragma unroll
    for (int s = 32; s; s >>= 1) rmax = fmaxf(rmax, __shfl_xor(rmax, s));
    // softmax denominator
    float rsum = 0.f;
#pragma unroll
    for (int i = 0; i < 16; ++i) rsum += __expf(v[i] - rmax);
#pragma unroll
    for (int s = 32; s; s >>= 1) rsum += __shfl_xor(rsum, s);

    unsigned int kb[16];
#pragma unroll
    for (int i = 0; i < 16; ++i) kb[i] = ford(v[i]);

    unsigned inmask = 0xFFFFu;
    unsigned need = 32, prefix = 0, lasth = 0;
#pragma unroll
    for (int level = 0; level < 3; ++level) {
        int shift = 24 - level * 8;
        ((uint4*)h)[lane] = make_uint4(0u, 0u, 0u, 0u);
        __syncthreads();
#pragma unroll
        for (int i = 0; i < 16; ++i)
            if ((inmask >> i) & 1u) atomicAdd(&h[(kb[i] >> shift) & 0xFFu], 1u);
        __syncthreads();
        uint4 hv = ((const uint4*)h)[lane];
        unsigned sl = hv.x + hv.y + hv.z + hv.w;
        unsigned S = sl;
#pragma unroll
        for (int off = 1; off < 64; off <<= 1) {
            unsigned o = __shfl_down(S, off);
            if (lane + off < 64) S += o;
        }
        unsigned above = S - sl;
        unsigned cg3 = above + hv.w;
        unsigned cg2 = cg3 + hv.z;
        unsigned cg1 = cg2 + hv.y;
        unsigned cg0 = cg1 + hv.x;
        unsigned pack = 0;
        if      (cg3 >= need) pack = ((4u * lane + 3u) << 12) | cg3;
        else if (cg2 >= need) pack = ((4u * lane + 2u) << 12) | cg2;
        else if (cg1 >= need) pack = ((4u * lane + 1u) << 12) | cg1;
        else if (cg0 >= need) pack = ((4u * lane + 0u) << 12) | cg0;
#pragma unroll
        for (int s = 32; s; s >>= 1) {
            unsigned o = __shfl_xor(pack, s);
            pack = o > pack ? o : pack;
        }
        unsigned bstar = pack >> 12, cstar = pack & 0xFFFu;
        unsigned hstar = h[bstar];
        need -= (cstar - hstar);
        prefix = (prefix << 8) | bstar;
        lasth = hstar;
        unsigned nm = 0;
#pragma unroll
        for (int i = 0; i < 16; ++i)
            if (((inmask >> i) & 1u) && ((kb[i] >> shift) & 0xFFu) == bstar)
                nm |= 1u << i;
        inmask = nm;
        __syncthreads();
    }

    unsigned winmask = 0;
    if (lasth == need) {
        winmask = inmask;
    } else {
        unsigned avail = inmask;
        unsigned long long best = 0ULL;
#pragma unroll
        for (int i = 0; i < 16; ++i)
            if ((avail >> i) & 1u) {
                int j = (i >> 2) * 256 + lane * 4 + (i & 3);
                unsigned long long k64 =
                    ((unsigned long long)kb[i] << 32) | (unsigned int)(~j);
                best = k64 > best ? k64 : best;
            }
        for (unsigned k = 0; k < need; ++k) {
            unsigned long long w = best;
#pragma unroll
            for (int s = 32; s; s >>= 1) {
                unsigned long long o = __shfl_xor(w, s);
                if (o > w) w = o;
            }
            if (best == w) {
                unsigned long long nb = 0ULL;
#pragma unroll
                for (int i = 0; i < 16; ++i)
                    if ((avail >> i) & 1u) {
                        int j = (i >> 2) * 256 + lane * 4 + (i & 3);
                        unsigned long long k64 =
                            ((unsigned long long)kb[i] << 32) | (unsigned int)(~j);
                        if (k64 == w) { winmask |= 1u << i; avail &= ~(1u << i); }
                        else nb = k64 > nb ? k64 : nb;
                    }
                best = nb;
            }
        }
    }

    if (lane == 0) wcnt[wave] = 0;
#pragma unroll
    for (int i = 0; i < 16; ++i) {
        bool wn = ((kb[i] >> 8) > prefix) || ((winmask >> i) & 1u);
        if (wn) {
            unsigned slot = atomicAdd(&wcnt[wave], 1u);
            int j = (i >> 2) * 256 + lane * 4 + (i & 3);
            tidx[(size_t)rb * 32 + slot] = (unsigned int)j;
            tval[(size_t)rb * 32 + slot] = __expf(v[i] - rmax) / rsum;
        }
    }
}

// ---------------- final: out = scatter(sov * x.wT[soi]) + sum_k siv_k*x_c*W[c,:] + bias
__global__ __launch_bounds__(256) void final_k(
    const float* __restrict__ x, const float* __restrict__ W,
    const float* __restrict__ wT, const float* __restrict__ bias,
    const unsigned int* __restrict__ tidx, const float* __restrict__ tval,
    float* __restrict__ out) {
    int n = blockIdx.x, t = threadIdx.x, wave = t >> 6, lane = t & 63;
    __shared__ float xr[1024];
    __shared__ float dres[32];
    __shared__ unsigned int gidx[32]; __shared__ float gval[32];
    __shared__ unsigned int iidx[32]; __shared__ float ival[32];

    ((float4*)xr)[t] = ((const float4*)(x + (size_t)n * 1024))[t];
    if (t < 32) {
        gidx[t] = tidx[(size_t)n * 32 + t];
        gval[t] = tval[(size_t)n * 32 + t];
    } else if (t < 64) {
        int k = t - 32;
        iidx[k] = tidx[((size_t)4096 + n) * 32 + k];
        ival[k] = tval[((size_t)4096 + n) * 32 + k];
    }
    __syncthreads();  // B1

    if (t < 32) ival[t] *= xr[iidx[t]];  // g_k = s_v_in * x[c_k]

    const float4* xr4 = (const float4*)xr;
#pragma unroll
    for (int d8 = 0; d8 < 8; ++d8) {
        int d = wave * 8 + d8;
        const float4* wrow = (const float4*)(wT + (size_t)gidx[d] * 1024);
        float s = 0.f;
#pragma unroll
        for (int q = 0; q < 4; ++q) {
            float4 a = wrow[q * 64 + lane];
            float4 b = xr4[q * 64 + lane];
            s += a.x * b.x + a.y * b.y + a.z * b.z + a.w * b.w;
        }
#pragma unroll
        for (int sft = 32; sft; sft >>= 1) s += __shfl_xor(s, sft);
        if (lane == 0) dres[d] = s * gval[d];
    }
    __syncthreads();  // B2

    float4 acc = ((const float4*)bias)[t];
    for (int k = 0; k < 32; ++k) {
        float g = ival[k];
        unsigned int c = iidx[k];
        float4 wr = ((const float4*)(W + (size_t)c * 1024))[t];
        acc.x = fmaf(g, wr.x, acc.x); acc.y = fmaf(g, wr.y, acc.y);
        acc.z = fmaf(g, wr.z, acc.z); acc.w = fmaf(g, wr.w, acc.w);
    }
    ((float4*)xr)[t] = acc;
    __syncthreads();  // B3
    if (t < 32) xr[gidx[t]] += dres[t];
    __syncthreads();  // B4
    ((float4*)(out + (size_t)n * 1024))[t] = ((float4*)xr)[t];
}

extern "C" void kernel_launch(void* const* d_in, const int* in_sizes, int n_in,
                              void* d_out, int out_size, void* d_ws, size_t ws_size,
                              hipStream_t stream) {
    (void)in_sizes; (void)n_in; (void)out_size; (void)ws_size;
    const float* x        = (const float*)d_in[0];
    const float* W        = (const float*)d_in[1];
    const float* bias     = (const float*)d_in[2];
    const float* so_cw    = (const float*)d_in[3];
    const float* so_cb    = (const float*)d_in[4];
    const float* so_gm    = (const float*)d_in[5];
    const float* so_bt    = (const float*)d_in[6];
    const float* so_lw    = (const float*)d_in[7];
    const float* so_lb    = (const float*)d_in[8];
    const float* si_cw    = (const float*)d_in[9];
    const float* si_cb    = (const float*)d_in[10];
    const float* si_gm    = (const float*)d_in[11];
    const float* si_bt    = (const float*)d_in[12];
    const float* si_lw    = (const float*)d_in[13];
    const float* si_lb    = (const float*)d_in[14];
    float* out = (float*)d_out;

    float* ws       = (float*)d_ws;
    float* wT       = ws;                       // 1048576
    unsigned short* whl = (unsigned short*)(ws + 1048576);  // 1048576 ushorts = 2MB
    float* xc       = ws + 1572864;             // 2 x 1048576
    float* partials = ws + 3670016;             // 262144
    float* sc       = ws + 3932160;             // 1024
    float* logits   = ws + 3933184;             // 8388608
    unsigned int* tidx = (unsigned int*)(ws + 12321792);  // 262144
    float* tval     = ws + 12583936;            // 262144

    transpose_k<<<dim3(32, 32), dim3(32, 8), 0, stream>>>(W, wT, 1024, 1024);
    wsplit_k<<<256, 256, 0, stream>>>(so_lw, si_lw, whl);
    conv_stats_k<<<256, 256, 0, stream>>>(x, so_cw, so_cb, si_cw, si_cb, xc, partials);
    stats_k<<<2, 256, 0, stream>>>(partials, so_gm, so_bt, si_gm, si_bt, sc);
    logits_mfma_k<<<dim3(64, 4, 2), 256, 0, stream>>>(xc, sc, whl, so_lb, si_lb, logits);
    topk_k<<<2048, 256, 0, stream>>>(logits, tidx, tval);
    final_k<<<4096, 256, 0, stream>>>(x, W, wT, bias, tidx, tval, out);
}

// Round 10
// 131.393 us; speedup vs baseline: 1.3382x; 1.0164x over previous
//
#include <hip/hip_runtime.h>
#include <math.h>

// Problem: B=4, L=1024, C1=1024, C2=1024, K=32, K_IN=32, g=256.
// N = B*L = 4096 rows. All f32.
//
// ws layout (floats):
//   wT      [1024*1024]            off 0
//   whl     [524288 f32-equiv]     off 1048576  (bf16 hi/lo split weights, 2MB)
//   xc      [2][4096*256]          off 1572864
//   partials[256][4][256]          off 3670016
//   sc      [2][2][256]            off 3932160
//   logits  [8192][1024]           off 3933184
//   tidx    [8192][32] (u32)       off 12321792
//   tval    [8192][32]             off 12583936
//   dres    [4096][32]             off 12846080
// total ~12.98M floats = 51.9 MB

typedef __attribute__((ext_vector_type(8))) short short8;
typedef __attribute__((ext_vector_type(4))) float f32x4;

__device__ __forceinline__ unsigned int ford(float f) {
    unsigned int b = __float_as_uint(f);
    return (b & 0x80000000u) ? ~b : (b | 0x80000000u);
}

// ---------------- generic 32x32 tiled transpose: in (R,C) -> out (C,R) -------
__global__ __launch_bounds__(256) void transpose_k(const float* __restrict__ in,
                                                   float* __restrict__ out,
                                                   int R, int C) {
    __shared__ float tile[32][33];
    int c0 = blockIdx.x * 32, r0 = blockIdx.y * 32;
    int tx = threadIdx.x, ty = threadIdx.y;  // block (32,8)
#pragma unroll
    for (int i = 0; i < 32; i += 8)
        tile[ty + i][tx] = in[(size_t)(r0 + ty + i) * C + c0 + tx];
    __syncthreads();
#pragma unroll
    for (int i = 0; i < 32; i += 8)
        out[(size_t)(c0 + ty + i) * R + r0 + tx] = tile[tx][ty + i];
}

// ---------------- split lin_w (f32 [1024 col][256 k]) into bf16 hi/lo frags --
// Fragment layout for mfma_f32_16x16x32_bf16 B operand: tile (ct,kt), lane l
// holds col = ct*16 + (l&15), k = kt*32 + (l>>4)*8 + j (j=0..7, 16 B).
__global__ __launch_bounds__(256) void wsplit_k(
    const float* __restrict__ so_lw, const float* __restrict__ si_lw,
    unsigned short* __restrict__ whl) {
    int g = blockIdx.x * 256 + threadIdx.x;  // 0..65535
    int br = g >> 15;
    int rem = g & 32767;
    int ct = rem >> 9;
    int kt = (rem >> 6) & 7;
    int l  = rem & 63;
    int col = ct * 16 + (l & 15);
    int ks  = kt * 32 + (l >> 4) * 8;
    const float* lw = (br ? si_lw : so_lw) + (size_t)col * 256 + ks;
    float4 v0 = *(const float4*)lw;
    float4 v1 = *(const float4*)(lw + 4);
    unsigned hh[8], ll[8];
#pragma unroll
    for (int j = 0; j < 8; ++j) {
        float a = j < 4 ? (&v0.x)[j] : (&v1.x)[j - 4];
        unsigned b = __float_as_uint(a);
        unsigned rh = (b + 0x7FFFu + ((b >> 16) & 1u)) & 0xFFFF0000u;
        hh[j] = rh >> 16;
        float res = a - __uint_as_float(rh);
        unsigned c = __float_as_uint(res);
        unsigned rl = (c + 0x7FFFu + ((c >> 16) & 1u)) & 0xFFFF0000u;
        ll[j] = rl >> 16;
    }
    uint4 ph, pl;
    ph.x = hh[0] | (hh[1] << 16); ph.y = hh[2] | (hh[3] << 16);
    ph.z = hh[4] | (hh[5] << 16); ph.w = hh[6] | (hh[7] << 16);
    pl.x = ll[0] | (ll[1] << 16); pl.y = ll[2] | (ll[3] << 16);
    pl.z = ll[4] | (ll[5] << 16); pl.w = ll[6] | (ll[7] << 16);
    size_t base = (((((size_t)br * 2 + 0) * 64 + ct) * 8 + kt) * 64 + l) * 8;
    size_t hstride = (size_t)64 * 8 * 64 * 8;  // h=0 -> h=1
    *(uint4*)&whl[base]           = ph;
    *(uint4*)&whl[base + hstride] = pl;
}

// ---------------- grouped 1x1 conv (4->1) for both branches + partial stats --
__global__ __launch_bounds__(256) void conv_stats_k(
    const float* __restrict__ x,
    const float* __restrict__ so_w, const float* __restrict__ so_b,
    const float* __restrict__ si_w, const float* __restrict__ si_b,
    float* __restrict__ xc, float* __restrict__ partials) {
    int g = threadIdx.x;          // channel 0..255
    int n0 = blockIdx.x * 16;     // 256 blocks x 16 rows
    float4 wo = ((const float4*)so_w)[g]; float bo = so_b[g];
    float4 wi = ((const float4*)si_w)[g]; float bi = si_b[g];
    float so_s = 0.f, so_q = 0.f, si_s = 0.f, si_q = 0.f;
#pragma unroll
    for (int r = 0; r < 16; ++r) {
        int n = n0 + r;
        float4 xv = ((const float4*)x)[n * 256 + g];
        float co = fmaf(xv.x, wo.x, fmaf(xv.y, wo.y, fmaf(xv.z, wo.z, fmaf(xv.w, wo.w, bo))));
        float ci = fmaf(xv.x, wi.x, fmaf(xv.y, wi.y, fmaf(xv.z, wi.z, fmaf(xv.w, wi.w, bi))));
        xc[n * 256 + g] = co;
        xc[1048576 + n * 256 + g] = ci;
        so_s += co; so_q += co * co;
        si_s += ci; si_q += ci * ci;
    }
    int b = blockIdx.x;
    partials[(b * 4 + 0) * 256 + g] = so_s;
    partials[(b * 4 + 1) * 256 + g] = so_q;
    partials[(b * 4 + 2) * 256 + g] = si_s;
    partials[(b * 4 + 3) * 256 + g] = si_q;
}

// ---------------- finalize BN stats -> per-channel scale/shift ---------------
__global__ __launch_bounds__(256) void stats_k(
    const float* __restrict__ partials,
    const float* __restrict__ g_so, const float* __restrict__ b_so,
    const float* __restrict__ g_si, const float* __restrict__ b_si,
    float* __restrict__ sc) {
    int g = threadIdx.x;
    int br = blockIdx.x;  // 0 = so, 1 = si
    float s = 0.f, q = 0.f;
    for (int b = 0; b < 256; ++b) {
        s += partials[(b * 4 + br * 2 + 0) * 256 + g];
        q += partials[(b * 4 + br * 2 + 1) * 256 + g];
    }
    float mean = s * (1.f / 4096.f);
    float var  = q * (1.f / 4096.f) - mean * mean;  // biased, matches ref
    float rstd = rsqrtf(var + 1e-5f);
    float gm = br ? g_si[g] : g_so[g];
    float bt = br ? b_si[g] : b_so[g];
    float scale = gm * rstd;
    sc[br * 512 + g]       = scale;
    sc[br * 512 + 256 + g] = fmaf(-mean, scale, bt);
}

// ---------------- BN+GELU fused + bf16x4-split MFMA logits GEMM --------------
__global__ __launch_bounds__(256, 2) void logits_mfma_k(
    const float* __restrict__ xc, const float* __restrict__ sc,
    const unsigned short* __restrict__ whl,
    const float* __restrict__ so_lb, const float* __restrict__ si_lb,
    float* __restrict__ logits) {
    __shared__ unsigned short ah[2048 * 8];  // 32 KB
    __shared__ unsigned short al[2048 * 8];  // 32 KB
    int t = threadIdx.x;
    int n0 = blockIdx.x * 64;
    int cb = blockIdx.y;          // 256-col block
    int br = blockIdx.z;
    int wave = t >> 6, lane = t & 63;

    const float* xcb = xc + (size_t)br * 1048576;
    const float* scp = sc + br * 512;

    // ---- stage xa hi/lo in fragment layout: slot s=(rt,kt,l), 8 elems ----
#pragma unroll
    for (int i = 0; i < 8; ++i) {
        int s = t + 256 * i;
        int rt = s >> 9, kt = (s >> 6) & 7, l = s & 63;
        int row = n0 + rt * 16 + (l & 15);
        int ks = kt * 32 + (l >> 4) * 8;
        const float* xp = xcb + (size_t)row * 256 + ks;
        float4 c0 = *(const float4*)xp;
        float4 c1 = *(const float4*)(xp + 4);
        float4 s0 = *(const float4*)(scp + ks);
        float4 s1 = *(const float4*)(scp + ks + 4);
        float4 h0 = *(const float4*)(scp + 256 + ks);
        float4 h1 = *(const float4*)(scp + 256 + ks + 4);
        unsigned hh[8], ll[8];
#pragma unroll
        for (int j = 0; j < 8; ++j) {
            float cv  = j < 4 ? (&c0.x)[j] : (&c1.x)[j - 4];
            float scl = j < 4 ? (&s0.x)[j] : (&s1.x)[j - 4];
            float shf = j < 4 ? (&h0.x)[j] : (&h1.x)[j - 4];
            float z = fmaf(cv, scl, shf);
            float a = 0.5f * z * (1.f + erff(z * 0.70710678f));
            unsigned b = __float_as_uint(a);
            unsigned rh = (b + 0x7FFFu + ((b >> 16) & 1u)) & 0xFFFF0000u;
            hh[j] = rh >> 16;
            float res = a - __uint_as_float(rh);
            unsigned cc = __float_as_uint(res);
            unsigned rl = (cc + 0x7FFFu + ((cc >> 16) & 1u)) & 0xFFFF0000u;
            ll[j] = rl >> 16;
        }
        uint4 ph, pl;
        ph.x = hh[0] | (hh[1] << 16); ph.y = hh[2] | (hh[3] << 16);
        ph.z = hh[4] | (hh[5] << 16); ph.w = hh[6] | (hh[7] << 16);
        pl.x = ll[0] | (ll[1] << 16); pl.y = ll[2] | (ll[3] << 16);
        pl.z = ll[4] | (ll[5] << 16); pl.w = ll[6] | (ll[7] << 16);
        *(uint4*)&ah[(size_t)s * 8] = ph;
        *(uint4*)&al[(size_t)s * 8] = pl;
    }
    __syncthreads();

    f32x4 acc[4][4];  // [ci][rt]
#pragma unroll
    for (int ci = 0; ci < 4; ++ci)
#pragma unroll
        for (int rt = 0; rt < 4; ++rt) acc[ci][rt] = (f32x4){0.f, 0.f, 0.f, 0.f};

    const size_t hstride = (size_t)64 * 8 * 64 * 8;
#pragma unroll 2
    for (int kt = 0; kt < 8; ++kt) {
        short8 Ah[4], Al[4];
#pragma unroll
        for (int rt = 0; rt < 4; ++rt) {
            Ah[rt] = *(const short8*)&ah[(((rt * 8 + kt) * 64) + lane) * 8];
            Al[rt] = *(const short8*)&al[(((rt * 8 + kt) * 64) + lane) * 8];
        }
#pragma unroll
        for (int ci = 0; ci < 4; ++ci) {
            int ctg = cb * 16 + wave * 4 + ci;
            size_t boff = ((((size_t)br * 2 + 0) * 64 + ctg) * 8 + kt) * 64 * 8 +
                          (size_t)lane * 8;
            short8 Wh = *(const short8*)&whl[boff];
            short8 Wl = *(const short8*)&whl[boff + hstride];
#pragma unroll
            for (int rt = 0; rt < 4; ++rt) {
                acc[ci][rt] = __builtin_amdgcn_mfma_f32_16x16x32_bf16(Ah[rt], Wh, acc[ci][rt], 0, 0, 0);
                acc[ci][rt] = __builtin_amdgcn_mfma_f32_16x16x32_bf16(Ah[rt], Wl, acc[ci][rt], 0, 0, 0);
                acc[ci][rt] = __builtin_amdgcn_mfma_f32_16x16x32_bf16(Al[rt], Wh, acc[ci][rt], 0, 0, 0);
                acc[ci][rt] = __builtin_amdgcn_mfma_f32_16x16x32_bf16(Al[rt], Wl, acc[ci][rt], 0, 0, 0);
            }
        }
    }

    // ---- epilogue: + bias, store f32 logits. C/D: col=lane&15, row=(lane>>4)*4+i
    const float* lb = br ? si_lb : so_lb;
#pragma unroll
    for (int ci = 0; ci < 4; ++ci) {
        int colg = cb * 256 + (wave * 4 + ci) * 16 + (lane & 15);
        float lbv = lb[colg];
#pragma unroll
        for (int rt = 0; rt < 4; ++rt) {
#pragma unroll
            for (int i = 0; i < 4; ++i) {
                int row = n0 + rt * 16 + (lane >> 4) * 4 + i;
                logits[((size_t)br * 4096 + row) * 1024 + colg] = acc[ci][rt][i] + lbv;
            }
        }
    }
}

// ---------------- softmax stats + exact top-32 per row-branch ----------------
__global__ __launch_bounds__(256) void topk_k(const float* __restrict__ logits,
                                              unsigned int* __restrict__ tidx,
                                              float* __restrict__ tval) {
    __shared__ unsigned int hist[4][256];
    __shared__ unsigned int wcnt[4];
    int wave = threadIdx.x >> 6, lane = threadIdx.x & 63;
    int rb = blockIdx.x * 4 + wave;  // 0..8191
    unsigned int* h = hist[wave];

    const float4* lg = (const float4*)(logits + (size_t)rb * 1024);
    float v[16];
#pragma unroll
    for (int q = 0; q < 4; ++q) {
        float4 f = lg[q * 64 + lane];
        v[q * 4 + 0] = f.x; v[q * 4 + 1] = f.y;
        v[q * 4 + 2] = f.z; v[q * 4 + 3] = f.w;
    }
    // row max
    float rmax = v[0];
#pragma unroll
    for (int i = 1; i < 16; ++i) rmax = fmaxf(rmax, v[i]);
#pragma unroll
    for (int s = 32; s; s >>= 1) rmax = fmaxf(rmax, __shfl_xor(rmax, s));
    // softmax denominator
    float rsum = 0.f;
#pragma unroll
    for (int i = 0; i < 16; ++i) rsum += __expf(v[i] - rmax);
#pragma unroll
    for (int s = 32; s; s >>= 1) rsum += __shfl_xor(rsum, s);

    unsigned int kb[16];
#pragma unroll
    for (int i = 0; i < 16; ++i) kb[i] = ford(v[i]);

    unsigned inmask = 0xFFFFu;
    unsigned need = 32, prefix = 0, lasth = 0;
#pragma unroll
    for (int level = 0; level < 3; ++level) {
        int shift = 24 - level * 8;
        ((uint4*)h)[lane] = make_uint4(0u, 0u, 0u, 0u);
        __syncthreads();
#pragma unroll
        for (int i = 0; i < 16; ++i)
            if ((inmask >> i) & 1u) atomicAdd(&h[(kb[i] >> shift) & 0xFFu], 1u);
        __syncthreads();
        uint4 hv = ((const uint4*)h)[lane];
        unsigned sl = hv.x + hv.y + hv.z + hv.w;
        unsigned S = sl;
#pragma unroll
        for (int off = 1; off < 64; off <<= 1) {
            unsigned o = __shfl_down(S, off);
            if (lane + off < 64) S += o;
        }
        unsigned above = S - sl;
        unsigned cg3 = above + hv.w;
        unsigned cg2 = cg3 + hv.z;
        unsigned cg1 = cg2 + hv.y;
        unsigned cg0 = cg1 + hv.x;
        unsigned pack = 0;
        if      (cg3 >= need) pack = ((4u * lane + 3u) << 12) | cg3;
        else if (cg2 >= need) pack = ((4u * lane + 2u) << 12) | cg2;
        else if (cg1 >= need) pack = ((4u * lane + 1u) << 12) | cg1;
        else if (cg0 >= need) pack = ((4u * lane + 0u) << 12) | cg0;
#pragma unroll
        for (int s = 32; s; s >>= 1) {
            unsigned o = __shfl_xor(pack, s);
            pack = o > pack ? o : pack;
        }
        unsigned bstar = pack >> 12, cstar = pack & 0xFFFu;
        unsigned hstar = h[bstar];
        need -= (cstar - hstar);
        prefix = (prefix << 8) | bstar;
        lasth = hstar;
        unsigned nm = 0;
#pragma unroll
        for (int i = 0; i < 16; ++i)
            if (((inmask >> i) & 1u) && ((kb[i] >> shift) & 0xFFu) == bstar)
                nm |= 1u << i;
        inmask = nm;
        __syncthreads();
    }

    unsigned winmask = 0;
    if (lasth == need) {
        winmask = inmask;
    } else {
        unsigned avail = inmask;
        unsigned long long best = 0ULL;
#pragma unroll
        for (int i = 0; i < 16; ++i)
            if ((avail >> i) & 1u) {
                int j = (i >> 2) * 256 + lane * 4 + (i & 3);
                unsigned long long k64 =
                    ((unsigned long long)kb[i] << 32) | (unsigned int)(~j);
                best = k64 > best ? k64 : best;
            }
        for (unsigned k = 0; k < need; ++k) {
            unsigned long long w = best;
#pragma unroll
            for (int s = 32; s; s >>= 1) {
                unsigned long long o = __shfl_xor(w, s);
                if (o > w) w = o;
            }
            if (best == w) {
                unsigned long long nb = 0ULL;
#pragma unroll
                for (int i = 0; i < 16; ++i)
                    if ((avail >> i) & 1u) {
                        int j = (i >> 2) * 256 + lane * 4 + (i & 3);
                        unsigned long long k64 =
                            ((unsigned long long)kb[i] << 32) | (unsigned int)(~j);
                        if (k64 == w) { winmask |= 1u << i; avail &= ~(1u << i); }
                        else nb = k64 > nb ? k64 : nb;
                    }
                best = nb;
            }
        }
    }

    if (lane == 0) wcnt[wave] = 0;
#pragma unroll
    for (int i = 0; i < 16; ++i) {
        bool wn = ((kb[i] >> 8) > prefix) || ((winmask >> i) & 1u);
        if (wn) {
            unsigned slot = atomicAdd(&wcnt[wave], 1u);
            int j = (i >> 2) * 256 + lane * 4 + (i & 3);
            tidx[(size_t)rb * 32 + slot] = (unsigned int)j;
            tval[(size_t)rb * 32 + slot] = __expf(v[i] - rmax) / rsum;
        }
    }
}

// ---------------- final pass A: out-branch gathered dots ---------------------
// dres[n][d] = s_v_out[d] * dot(x[n], wT[gidx[d]]). Weight working set = wT
// (4 MB) only -> fits per-XCD L2 -> gathers are L2 hits after warm-up.
__global__ __launch_bounds__(256) void finalA_k(
    const float* __restrict__ x, const float* __restrict__ wT,
    const unsigned int* __restrict__ tidx, const float* __restrict__ tval,
    float* __restrict__ dres) {
    int n = blockIdx.x, t = threadIdx.x, wave = t >> 6, lane = t & 63;
    __shared__ float xr[1024];
    __shared__ unsigned int gidx[32]; __shared__ float gval[32];

    ((float4*)xr)[t] = ((const float4*)(x + (size_t)n * 1024))[t];
    if (t < 32) {
        gidx[t] = tidx[(size_t)n * 32 + t];
        gval[t] = tval[(size_t)n * 32 + t];
    }
    __syncthreads();

    const float4* xr4 = (const float4*)xr;
#pragma unroll
    for (int d8 = 0; d8 < 8; ++d8) {
        int d = wave * 8 + d8;
        const float4* wrow = (const float4*)(wT + (size_t)gidx[d] * 1024);
        float s = 0.f;
#pragma unroll
        for (int q = 0; q < 4; ++q) {
            float4 a = wrow[q * 64 + lane];
            float4 b = xr4[q * 64 + lane];
            s += a.x * b.x + a.y * b.y + a.z * b.z + a.w * b.w;
        }
#pragma unroll
        for (int sft = 32; sft; sft >>= 1) s += __shfl_xor(s, sft);
        if (lane == 0) dres[(size_t)n * 32 + d] = s * gval[d];
    }
}

// ---------------- final pass B: in-branch axpys + assemble -------------------
// out[n,:] = bias + sum_k ival_k * W[iidx_k,:] + scatter(dres[n,:] at gidx).
// Weight working set = W (4 MB) only -> L2-resident.
__global__ __launch_bounds__(256) void finalB_k(
    const float* __restrict__ x, const float* __restrict__ W,
    const float* __restrict__ bias,
    const unsigned int* __restrict__ tidx, const float* __restrict__ tval,
    const float* __restrict__ dres, float* __restrict__ out) {
    int n = blockIdx.x, t = threadIdx.x;
    __shared__ float xr[1024];
    __shared__ unsigned int iidx[32]; __shared__ float ival[32];
    __shared__ unsigned int gidx[32]; __shared__ float dr[32];

    if (t < 32) {
        unsigned c = tidx[((size_t)4096 + n) * 32 + t];
        iidx[t] = c;
        ival[t] = tval[((size_t)4096 + n) * 32 + t] * x[(size_t)n * 1024 + c];
    } else if (t < 64) {
        int k = t - 32;
        gidx[k] = tidx[(size_t)n * 32 + k];
        dr[k]   = dres[(size_t)n * 32 + k];
    }
    __syncthreads();

    float4 acc = ((const float4*)bias)[t];
    for (int k = 0; k < 32; ++k) {
        float g = ival[k];
        unsigned int c = iidx[k];
        float4 wr = ((const float4*)(W + (size_t)c * 1024))[t];
        acc.x = fmaf(g, wr.x, acc.x); acc.y = fmaf(g, wr.y, acc.y);
        acc.z = fmaf(g, wr.z, acc.z); acc.w = fmaf(g, wr.w, acc.w);
    }
    ((float4*)xr)[t] = acc;
    __syncthreads();
    if (t < 32) xr[gidx[t]] += dr[t];  // unique indices, no race
    __syncthreads();
    ((float4*)(out + (size_t)n * 1024))[t] = ((float4*)xr)[t];
}

extern "C" void kernel_launch(void* const* d_in, const int* in_sizes, int n_in,
                              void* d_out, int out_size, void* d_ws, size_t ws_size,
                              hipStream_t stream) {
    (void)in_sizes; (void)n_in; (void)out_size; (void)ws_size;
    const float* x        = (const float*)d_in[0];
    const float* W        = (const float*)d_in[1];
    const float* bias     = (const float*)d_in[2];
    const float* so_cw    = (const float*)d_in[3];
    const float* so_cb    = (const float*)d_in[4];
    const float* so_gm    = (const float*)d_in[5];
    const float* so_bt    = (const float*)d_in[6];
    const float* so_lw    = (const float*)d_in[7];
    const float* so_lb    = (const float*)d_in[8];
    const float* si_cw    = (const float*)d_in[9];
    const float* si_cb    = (const float*)d_in[10];
    const float* si_gm    = (const float*)d_in[11];
    const float* si_bt    = (const float*)d_in[12];
    const float* si_lw    = (const float*)d_in[13];
    const float* si_lb    = (const float*)d_in[14];
    float* out = (float*)d_out;

    float* ws       = (float*)d_ws;
    float* wT       = ws;                       // 1048576
    unsigned short* whl = (unsigned short*)(ws + 1048576);  // 1048576 ushorts = 2MB
    float* xc       = ws + 1572864;             // 2 x 1048576
    float* partials = ws + 3670016;             // 262144
    float* sc       = ws + 3932160;             // 1024
    float* logits   = ws + 3933184;             // 8388608
    unsigned int* tidx = (unsigned int*)(ws + 12321792);  // 262144
    float* tval     = ws + 12583936;            // 262144
    float* dres     = ws + 12846080;            // 131072

    transpose_k<<<dim3(32, 32), dim3(32, 8), 0, stream>>>(W, wT, 1024, 1024);
    wsplit_k<<<256, 256, 0, stream>>>(so_lw, si_lw, whl);
    conv_stats_k<<<256, 256, 0, stream>>>(x, so_cw, so_cb, si_cw, si_cb, xc, partials);
    stats_k<<<2, 256, 0, stream>>>(partials, so_gm, so_bt, si_gm, si_bt, sc);
    logits_mfma_k<<<dim3(64, 4, 2), 256, 0, stream>>>(xc, sc, whl, so_lb, si_lb, logits);
    topk_k<<<2048, 256, 0, stream>>>(logits, tidx, tval);
    finalA_k<<<4096, 256, 0, stream>>>(x, wT, tidx, tval, dres);
    finalB_k<<<4096, 256, 0, stream>>>(x, W, bias, tidx, tval, dres, out);
}